// Round 8
// baseline (457.727 us; speedup 1.0000x reference)
//
#include <hip/hip_runtime.h>

typedef unsigned short u16;
typedef unsigned int u32;
typedef __attribute__((ext_vector_type(8))) short bf16x8;
typedef __attribute__((ext_vector_type(4))) float f32x4;

#define NPTS 2048
#define CFEAT 256
#define NS 32
#define MTOT 262144           // 4*2048*32
#define NBLK 4096             // MTOT/64 m-tiles
#define NROW 8192             // unique gathered rows = 4*2048
#define INV_N (1.0f/262144.0f)

__device__ __forceinline__ float bf2f(u16 u) {
    union { u32 i; float f; } v; v.i = ((u32)u) << 16; return v.f;
}
__device__ __forceinline__ u16 f2bf(float f) {
    union { float f; u32 i; } v; v.f = f;
    u32 i = v.i;
    return (u16)((i + 0x7fffu + ((i >> 16) & 1u)) >> 16);
}

// async global->LDS, 16B per lane (used only in zgemm_k; fused_k is pure reg-staged so
// private prefetch loads are not drained at barriers).
__device__ __forceinline__ void gload16(const void* g, void* l) {
    __builtin_amdgcn_global_load_lds((const __attribute__((address_space(1))) void*)g,
                                     (__attribute__((address_space(3))) void*)l, 16, 0, 0);
}

// ---------------- cylinder query + fused gxyz + folded W-prep (blocks 0..255) ----------------
__global__ __launch_bounds__(256) void query_k(const float* __restrict__ xyz, const float* __restrict__ rot,
                                               int* __restrict__ idx, u16* __restrict__ gxyz,
                                               const float* __restrict__ W1, const float* __restrict__ W2,
                                               u16* __restrict__ Wp1, u16* __restrict__ Wp2) {
    __shared__ int sidx[4 * NS];
    // folded prep: pack W1 -> [feat(256)|xyz(3)|0(29)] (K=288), W2 (K=256), bf16
    if (blockIdx.x < 256) {
        int o = blockIdx.x, t = threadIdx.x;
        Wp1[o * 288 + t] = f2bf(W1[o * 259 + 3 + t]);
        if (t < 32) Wp1[o * 288 + 256 + t] = (t < 3) ? f2bf(W1[o * 259 + t]) : (u16)0;
        Wp2[o * 256 + t] = f2bf(W2[o * 256 + t]);
    }
    const int wid = threadIdx.x >> 6;
    const int pid = blockIdx.x * 4 + wid;
    const int lane = threadIdx.x & 63;
    const int b = pid >> 11, p = pid & 2047;
    const float* xb = xyz + (size_t)b * NPTS * 3;
    float px = xb[p * 3 + 0], py = xb[p * 3 + 1], pz = xb[p * 3 + 2];
    const float* rp = rot + (size_t)pid * 9;
    float r00 = rp[0], r01 = rp[1], r02 = rp[2];
    float r10 = rp[3], r11 = rp[4], r12 = rp[5];
    float r20 = rp[6], r21 = rp[7], r22 = rp[8];
    int cnt = 0, first = 0;
    for (int n0 = 0; n0 < NPTS && cnt < NS; n0 += 64) {
        int n = n0 + lane;
        // exact fp32, sequential order, no fma contraction -> match numpy mask bitwise
        float dx = __fsub_rn(xb[n * 3 + 0], px);
        float dy = __fsub_rn(xb[n * 3 + 1], py);
        float dz = __fsub_rn(xb[n * 3 + 2], pz);
        float a0 = __fadd_rn(__fadd_rn(__fmul_rn(r00, dx), __fmul_rn(r01, dy)), __fmul_rn(r02, dz));
        float a1 = __fadd_rn(__fadd_rn(__fmul_rn(r10, dx), __fmul_rn(r11, dy)), __fmul_rn(r12, dz));
        float a2 = __fadd_rn(__fadd_rn(__fmul_rn(r20, dx), __fmul_rn(r21, dy)), __fmul_rn(r22, dz));
        float t2 = __fadd_rn(__fmul_rn(a1, a1), __fmul_rn(a2, a2));
        bool valid = (t2 < 0.0025f) && (a0 > -0.02f) && (a0 < 0.04f);
        unsigned long long bal = __ballot(valid);
        if (cnt == 0 && bal) first = n0 + __builtin_ctzll(bal);
        int rank = __builtin_popcountll(bal & ((1ull << lane) - 1ull));
        int slot = cnt + rank;
        if (valid && slot < NS) sidx[wid * NS + slot] = n;
        cnt += __builtin_popcountll(bal);
    }
    int filled = cnt < NS ? cnt : NS;
    __syncthreads();   // sidx visible (cheap; waves re-converge)
    if (lane < NS) {
        int i = (lane < filled) ? sidx[wid * NS + lane] : (cnt > 0 ? first : 0);
        idx[(size_t)pid * NS + lane] = i;
        // gxyz: rotated, scaled neighbor offset (same math as old gxyz_k)
        float dx = (xb[i * 3 + 0] - px) * 20.0f;
        float dy = (xb[i * 3 + 1] - py) * 20.0f;
        float dz = (xb[i * 3 + 2] - pz) * 20.0f;
        float g0 = dx * r00 + dy * r10 + dz * r20;
        float g1 = dx * r01 + dy * r11 + dz * r21;
        float g2 = dx * r02 + dy * r12 + dz * r22;
        uint2 v;
        v.x = (u32)f2bf(g0) | ((u32)f2bf(g1) << 16);
        v.y = (u32)f2bf(g2);
        *(uint2*)(gxyz + ((size_t)pid * NS + lane) * 4) = v;
    }
}

// ---------------- features (B,C,N) fp32 -> featT (B,N,C) bf16 ----------------
__global__ __launch_bounds__(256) void featT_k(const float* __restrict__ feat, u16* __restrict__ featT) {
    __shared__ float sm[32 * 33];
    int b = blockIdx.z;
    int n0 = blockIdx.x * 32, c0 = blockIdx.y * 32;
    int t = threadIdx.x, x = t & 31, y = t >> 5;
    #pragma unroll
    for (int rr = 0; rr < 4; rr++) {
        int c = c0 + y + rr * 8;
        sm[(y + rr * 8) * 33 + x] = feat[((size_t)(b * CFEAT + c)) * NPTS + n0 + x];
    }
    __syncthreads();
    #pragma unroll
    for (int rr = 0; rr < 4; rr++) {
        int n = n0 + y + rr * 8;
        featT[((size_t)(b * NPTS + n)) * CFEAT + c0 + x] = f2bf(sm[x * 33 + (y + rr * 8)]);
    }
}

// ---------------- histogram partials: 64 blocks (16/batch), private LDS hist, NO global atomics --------
// block 0 additionally zeroes the Sacc/Qacc/Xacc accumulators (768 floats, contiguous at Sacc).
__global__ __launch_bounds__(256) void hist_k(const int* __restrict__ idx, const u16* __restrict__ gxyz,
                                              float* __restrict__ hpart, float* __restrict__ xst64,
                                              float* __restrict__ Sacc) {
    __shared__ float hist[8192];       // 2048 rows x 4 (cnt,x0,x1,x2) = 32 KB
    __shared__ float red[9 * 4];
    const int t = threadIdx.x, lane = t & 63, wave = t >> 6;
    const int g = blockIdx.x;
    const int base = g * 4096;
    if (g == 0) { Sacc[t] = 0.f; Sacc[t + 256] = 0.f; Sacc[t + 512] = 0.f; }
    for (int i = t; i < 8192; i += 256) hist[i] = 0.f;
    __syncthreads();
    float p[9] = {0.f,0.f,0.f,0.f,0.f,0.f,0.f,0.f,0.f};
    for (int u = 0; u < 16; u++) {
        int m = base + u * 256 + t;
        int r = idx[m];                // local row 0..2047
        uint2 v = *(const uint2*)(gxyz + (size_t)m * 4);
        float x0 = bf2f((u16)(v.x & 0xffff));
        float x1 = bf2f((u16)(v.x >> 16));
        float x2 = bf2f((u16)(v.y & 0xffff));
        atomicAdd(hist + r * 4 + 0, 1.f);   // LDS atomics (ds_add_f32)
        atomicAdd(hist + r * 4 + 1, x0);
        atomicAdd(hist + r * 4 + 2, x1);
        atomicAdd(hist + r * 4 + 3, x2);
        p[0] += x0; p[1] += x1; p[2] += x2;
        p[3] += x0 * x0; p[4] += x0 * x1; p[5] += x0 * x2;
        p[6] += x1 * x1; p[7] += x1 * x2; p[8] += x2 * x2;
    }
    __syncthreads();
    for (int i = t; i < 8192; i += 256) hpart[(size_t)g * 8192 + i] = hist[i];
    #pragma unroll
    for (int k = 0; k < 9; k++) {
        float s = p[k];
        #pragma unroll
        for (int o = 1; o < 64; o <<= 1) s += __shfl_xor(s, o);
        if (lane == 0) red[k * 4 + wave] = s;
    }
    __syncthreads();
    if (t < 9) xst64[g * 9 + t] = red[t * 4 + 0] + red[t * 4 + 1] + red[t * 4 + 2] + red[t * 4 + 3];
}

// ---------------- z-GEMM over the 8192 unique rows + inline hpart merge + weighted stats1 ----------------
__global__ __launch_bounds__(256) void zgemm_k(const u16* __restrict__ featT, const u16* __restrict__ Wp1,
                                               const float* __restrict__ hpart,
                                               float* __restrict__ Sacc, float* __restrict__ Qacc,
                                               float* __restrict__ Xacc) {
    __shared__ __attribute__((aligned(16))) u16 As[64 * 32];
    __shared__ __attribute__((aligned(16))) u16 Bs[256 * 32];
    __shared__ float cxs[64 * 4];      // merged (cnt,x0,x1,x2) for this block's 64 rows
    const int tid = threadIdx.x;
    const int lane = tid & 63, wave = tid >> 6;
    const int quad = lane >> 4, tl = lane & 15;
    const int m0 = blockIdx.x * 64;
    const int srow = tid >> 2, sc16 = tid & 3;
    const int abase = (m0 + srow) * CFEAT + sc16 * 8;

    // inline merge of the 16 per-segment histogram partials for this block's rows (batch-local)
    {
        const int b = m0 >> 11;            // batch
        const int rl0 = m0 & 2047;         // local row base
        int row = tid >> 2, c = tid & 3;
        float s = 0.f;
        #pragma unroll
        for (int sg = 0; sg < 16; sg++)
            s += hpart[(size_t)(b * 16 + sg) * 8192 + (rl0 + row) * 4 + c];
        cxs[tid] = s;
    }

    f32x4 acc[4][4];
    #pragma unroll
    for (int i = 0; i < 4; i++)
        #pragma unroll
        for (int j = 0; j < 4; j++) acc[i][j] = (f32x4){0.f, 0.f, 0.f, 0.f};

    for (int ks = 0; ks < 8; ks++) {
        const int k0 = ks * 32;
        __syncthreads();
        gload16(featT + abase + k0, As + tid * 8);
        #pragma unroll
        for (int q = 0; q < 4; q++)
            gload16(Wp1 + (srow + q * 64) * 288 + k0 + sc16 * 8, Bs + q * 2048 + tid * 8);
        __syncthreads();
        bf16x8 af[4], bv[4];
        #pragma unroll
        for (int i = 0; i < 4; i++) af[i] = *(const bf16x8*)(As + (i * 16 + tl) * 32 + quad * 8);
        #pragma unroll
        for (int j = 0; j < 4; j++) bv[j] = *(const bf16x8*)(Bs + (wave * 64 + j * 16 + tl) * 32 + quad * 8);
        #pragma unroll
        for (int i = 0; i < 4; i++)
            #pragma unroll
            for (int j = 0; j < 4; j++)
                acc[i][j] = __builtin_amdgcn_mfma_f32_16x16x32_bf16(af[i], bv[j], acc[i][j], 0, 0, 0);
    }

    #pragma unroll
    for (int j = 0; j < 4; j++) {
        int col = wave * 64 + j * 16 + tl;
        float wx0 = bf2f(Wp1[col * 288 + 256]);
        float wx1 = bf2f(Wp1[col * 288 + 257]);
        float wx2 = bf2f(Wp1[col * 288 + 258]);
        float S = 0.f, Q = 0.f, X = 0.f;
        #pragma unroll
        for (int i = 0; i < 4; i++)
            #pragma unroll
            for (int rr = 0; rr < 4; rr++) {
                int row = i * 16 + quad * 4 + rr;
                float4 cx = *(const float4*)(cxs + row * 4);
                float z = acc[i][j][rr];
                S += cx.x * z;
                Q += cx.x * z * z;
                X += z * (wx0 * cx.y + wx1 * cx.z + wx2 * cx.w);
            }
        S += __shfl_xor(S, 16); S += __shfl_xor(S, 32);
        Q += __shfl_xor(Q, 16); Q += __shfl_xor(Q, 32);
        X += __shfl_xor(X, 16); X += __shfl_xor(X, 32);
        if (quad == 0) {
            atomicAdd(Sacc + col, S);
            atomicAdd(Qacc + col, Q);
            atomicAdd(Xacc + col, X);
        }
    }
}

// ---------------- assemble stats1 -> (a,b) affine ----------------
__global__ __launch_bounds__(256) void ab1_k(const float* __restrict__ Sacc, const float* __restrict__ Qacc,
                                             const float* __restrict__ Xacc, const float* __restrict__ xst64,
                                             const u16* __restrict__ Wp1,
                                             const float* __restrict__ gamma, const float* __restrict__ beta,
                                             float* __restrict__ ab) {
    int c = threadIdx.x;
    float xs[9] = {0.f,0.f,0.f,0.f,0.f,0.f,0.f,0.f,0.f};
    for (int g = 0; g < 64; g++)
        #pragma unroll
        for (int k = 0; k < 9; k++) xs[k] += xst64[g * 9 + k];
    float wx0 = bf2f(Wp1[c * 288 + 256]);
    float wx1 = bf2f(Wp1[c * 288 + 257]);
    float wx2 = bf2f(Wp1[c * 288 + 258]);
    float S = Sacc[c] + wx0 * xs[0] + wx1 * xs[1] + wx2 * xs[2];
    float qxx = wx0 * wx0 * xs[3] + wx1 * wx1 * xs[6] + wx2 * wx2 * xs[8]
              + 2.f * (wx0 * wx1 * xs[4] + wx0 * wx2 * xs[5] + wx1 * wx2 * xs[7]);
    float Q = Qacc[c] + 2.f * Xacc[c] + qxx;
    float mu = S * INV_N;
    float var = Q * INV_N - mu * mu;
    float a = gamma[c] * rsqrtf(var + 1e-5f);
    ab[c] = a;
    ab[256 + c] = beta[c] - mu * a;
}

// ---------------- fused m-tile kernel: reg-staged 1-ahead prefetch (T14), two barriers/phase --------
// col ownership: col = j*64 + wave*16 + tl. No global_load_lds here: pure reg staging so the
// in-flight private prefetch loads are NOT drained by the barriers.
template <int FULL>
__global__ __launch_bounds__(256, 3) void fused_k(
    const u16* __restrict__ featT, const u16* __restrict__ gxyz, const int* __restrict__ idx,
    const u16* __restrict__ Wp1, const u16* __restrict__ Wp2, const float* __restrict__ ab1,
    float* __restrict__ psum, float* __restrict__ psq,
    float* __restrict__ ymax, float* __restrict__ ymin)
{
    __shared__ __attribute__((aligned(16))) u16 As[64 * 32];                 //  4 KB
    __shared__ __attribute__((aligned(16))) u16 Bs[256 * 32];                // 16 KB
    __shared__ __attribute__((aligned(16))) u16 y1s[FULL ? 64 * 136 : 16];   // 17 KB (half of y1)
    __shared__ int rowbase_s[64];

    const int tid = threadIdx.x;
    const int lane = tid & 63, wave = tid >> 6;
    const int quad = lane >> 4, tl = lane & 15;
    const int bx = blockIdx.x;
    const int m0 = bx * 64;

    if (tid < 64) {
        int m = m0 + tid;
        int gi = idx[m];
        int b = m >> 16;
        rowbase_s[tid] = (b * NPTS + gi) * CFEAT;
    }
    __syncthreads();
    const int srow = tid >> 2, sc16 = tid & 3;
    const int abase = rowbase_s[srow] + sc16 * 8;

    // ---- prologue: issue loads for phase 0 (transient regs) ----
    uint4 va = *(const uint4*)(featT + abase);
    uint4 vb[4];
    #pragma unroll
    for (int q = 0; q < 4; q++)
        vb[q] = *(const uint4*)(Wp1 + (srow + q * 64) * 288 + sc16 * 8);
    uint2 vg = make_uint2(0, 0);
    if (sc16 == 0) vg = *(const uint2*)(gxyz + (size_t)(m0 + srow) * 4);

    f32x4 acc[4][4];
    #pragma unroll
    for (int i = 0; i < 4; i++)
        #pragma unroll
        for (int j = 0; j < 4; j++) acc[i][j] = (f32x4){0.f, 0.f, 0.f, 0.f};

    auto mfma_tile = [&](f32x4 (&ac)[4][4], const u16* a_lds, int a_stride) {
        bf16x8 af[4], bv2[4];
        #pragma unroll
        for (int i = 0; i < 4; i++) af[i] = *(const bf16x8*)(a_lds + (i * 16 + tl) * a_stride + quad * 8);
        #pragma unroll
        for (int j = 0; j < 4; j++) bv2[j] = *(const bf16x8*)(Bs + (j * 64 + wave * 16 + tl) * 32 + quad * 8);
        #pragma unroll
        for (int i = 0; i < 4; i++)
            #pragma unroll
            for (int j = 0; j < 4; j++)
                ac[i][j] = __builtin_amdgcn_mfma_f32_16x16x32_bf16(af[i], bv2[j], ac[i][j], 0, 0, 0);
    };

    // ---- GEMM1: 9 phases; deposit prefetched regs, issue next, compute ----
    #pragma unroll
    for (int t = 0; t < 9; t++) {
        __syncthreads();                               // prior phase's LDS reads done
        *(uint4*)(As + tid * 8) = va;                  // ds_write_b128 from regs
        #pragma unroll
        for (int q = 0; q < 4; q++)
            *(uint4*)(Bs + q * 2048 + tid * 8) = vb[q];
        if (t < 7) {                                   // issue phase t+1 loads (fly over the MFMAs)
            va = *(const uint4*)(featT + abase + (t + 1) * 32);
            #pragma unroll
            for (int q = 0; q < 4; q++)
                vb[q] = *(const uint4*)(Wp1 + (srow + q * 64) * 288 + (t + 1) * 32 + sc16 * 8);
        } else if (t == 7) {                           // phase 8 = xyz tile
            uint4 x = make_uint4(0, 0, 0, 0);
            if (sc16 == 0) { x.x = vg.x; x.y = vg.y; }
            va = x;
            #pragma unroll
            for (int q = 0; q < 4; q++)
                vb[q] = *(const uint4*)(Wp1 + (srow + q * 64) * 288 + 256 + sc16 * 8);
        }
        __syncthreads();                               // ds_writes visible (lgkm drain only)
        mfma_tile(acc, As, 32);
    }

    if (!FULL) {
        #pragma unroll
        for (int j = 0; j < 4; j++) {
            float s = 0.f, q2 = 0.f;
            #pragma unroll
            for (int i = 0; i < 4; i++) {
                s += acc[i][j][0] + acc[i][j][1] + acc[i][j][2] + acc[i][j][3];
                q2 += acc[i][j][0]*acc[i][j][0] + acc[i][j][1]*acc[i][j][1]
                    + acc[i][j][2]*acc[i][j][2] + acc[i][j][3]*acc[i][j][3];
            }
            s += __shfl_xor(s, 16); s += __shfl_xor(s, 32);
            q2 += __shfl_xor(q2, 16); q2 += __shfl_xor(q2, 32);
            if (quad == 0) {
                int col = j * 64 + wave * 16 + tl;
                psum[(size_t)bx * 256 + col] = s;
                psq[(size_t)bx * 256 + col] = q2;
            }
        }
        return;
    }

    // ---- GEMM2 prologue: issue Wp2 tile 0; write norm1 K-half 0 (channels 0..127) ----
    #pragma unroll
    for (int q = 0; q < 4; q++)
        vb[q] = *(const uint4*)(Wp2 + (srow + q * 64) * 256 + sc16 * 8);
    #pragma unroll
    for (int j = 0; j < 2; j++) {
        int col = j * 64 + wave * 16 + tl;          // < 128
        float a = ab1[col], bb = ab1[256 + col];
        #pragma unroll
        for (int i = 0; i < 4; i++)
            #pragma unroll
            for (int r = 0; r < 4; r++) {
                float v = fmaxf(fmaf(acc[i][j][r], a, bb), 0.f);
                y1s[(i * 16 + quad * 4 + r) * 136 + col] = f2bf(v);
            }
    }

    // ---- GEMM2: 8 phases; A = y1s half-buffer (swapped at ks==4), B = Wp2 reg-staged ----
    f32x4 acc2[4][4];
    #pragma unroll
    for (int i = 0; i < 4; i++)
        #pragma unroll
        for (int j = 0; j < 4; j++) acc2[i][j] = (f32x4){0.f, 0.f, 0.f, 0.f};
    #pragma unroll
    for (int ks = 0; ks < 8; ks++) {
        if (ks == 4) {
            __syncthreads();                         // all ks=3 reads of y1s done
            #pragma unroll
            for (int j = 2; j < 4; j++) {            // channels 128..255
                int col = j * 64 + wave * 16 + tl;
                int lc = col - 128;
                float a = ab1[col], bb = ab1[256 + col];
                #pragma unroll
                for (int i = 0; i < 4; i++)
                    #pragma unroll
                    for (int r = 0; r < 4; r++) {
                        float v = fmaxf(fmaf(acc[i][j][r], a, bb), 0.f);
                        y1s[(i * 16 + quad * 4 + r) * 136 + lc] = f2bf(v);
                    }
            }
        }
        __syncthreads();                             // prior phase's Bs reads done
        #pragma unroll
        for (int q = 0; q < 4; q++)
            *(uint4*)(Bs + q * 2048 + tid * 8) = vb[q];
        if (ks < 7) {
            #pragma unroll
            for (int q = 0; q < 4; q++)
                vb[q] = *(const uint4*)(Wp2 + (srow + q * 64) * 256 + (ks + 1) * 32 + sc16 * 8);
        }
        __syncthreads();                             // Bs + y1s writes visible
        mfma_tile(acc2, y1s + ((ks * 32) & 127), 136);
    }

    // ---- epilogue: stats2 + per-point max/min ----
    #pragma unroll
    for (int j = 0; j < 4; j++) {
        int col = j * 64 + wave * 16 + tl;
        float s = 0.f, q2 = 0.f;
        float mx0 = -3.0e38f, mn0 = 3.0e38f, mx1 = -3.0e38f, mn1 = 3.0e38f;
        #pragma unroll
        for (int i = 0; i < 4; i++)
            #pragma unroll
            for (int r = 0; r < 4; r++) {
                float v = acc2[i][j][r];
                s += v; q2 += v * v;
                if (i < 2) { mx0 = fmaxf(mx0, v); mn0 = fminf(mn0, v); }
                else       { mx1 = fmaxf(mx1, v); mn1 = fminf(mn1, v); }
            }
        s += __shfl_xor(s, 16); s += __shfl_xor(s, 32);
        q2 += __shfl_xor(q2, 16); q2 += __shfl_xor(q2, 32);
        mx0 = fmaxf(mx0, __shfl_xor(mx0, 16)); mx0 = fmaxf(mx0, __shfl_xor(mx0, 32));
        mn0 = fminf(mn0, __shfl_xor(mn0, 16)); mn0 = fminf(mn0, __shfl_xor(mn0, 32));
        mx1 = fmaxf(mx1, __shfl_xor(mx1, 16)); mx1 = fmaxf(mx1, __shfl_xor(mx1, 32));
        mn1 = fminf(mn1, __shfl_xor(mn1, 16)); mn1 = fminf(mn1, __shfl_xor(mn1, 32));
        if (quad == 0) {
            psum[(size_t)bx * 256 + col] = s;
            psq[(size_t)bx * 256 + col] = q2;
            size_t p0 = (size_t)(bx * 2) * 256 + col;
            size_t p1 = (size_t)(bx * 2 + 1) * 256 + col;
            ymax[p0] = mx0; ymin[p0] = mn0;
            ymax[p1] = mx1; ymin[p1] = mn1;
        }
    }
}

// ---------------- stats reduction: 64 blocks x 64 rows (coalesced), then 1-block finish ----------------
__global__ __launch_bounds__(256) void reduce1_k(const float* __restrict__ psum, const float* __restrict__ psq,
                                                 float* __restrict__ ps2, float* __restrict__ pq2) {
    int j = blockIdx.x, t = threadIdx.x;
    float s = 0.f, q = 0.f;
    #pragma unroll 4
    for (int kk = 0; kk < 64; kk++) {
        size_t r = (size_t)(j * 64 + kk) * 256 + t;
        s += psum[r]; q += psq[r];
    }
    ps2[j * 256 + t] = s;
    pq2[j * 256 + t] = q;
}

__global__ __launch_bounds__(256) void reduce2_k(const float* __restrict__ ps2, const float* __restrict__ pq2,
                                                 const float* __restrict__ gamma, const float* __restrict__ beta,
                                                 float* __restrict__ ab) {
    int c = threadIdx.x;
    float S = 0.f, Q = 0.f;
    for (int j = 0; j < 64; j++) {
        S += ps2[j * 256 + c];
        Q += pq2[j * 256 + c];
    }
    float mu = S * INV_N;
    float var = Q * INV_N - mu * mu;
    float a = gamma[c] * rsqrtf(var + 1e-5f);
    ab[c] = a;
    ab[256 + c] = beta[c] - mu * a;
}

// ---------------- final: relu(a*(a>=0?max:min)+b), transpose -> (B,O,N) ----------------
__global__ __launch_bounds__(256) void final_k(const float* __restrict__ ymax, const float* __restrict__ ymin,
                                               const float* __restrict__ ab, float* __restrict__ out) {
    __shared__ float sm[32 * 33];
    int b = blockIdx.z;
    int n0 = blockIdx.x * 32, o0 = blockIdx.y * 32;
    int t = threadIdx.x, x = t & 31, y = t >> 5;
    #pragma unroll
    for (int rr = 0; rr < 4; rr++) {
        int n = n0 + y + rr * 8;
        int o = o0 + x;
        float a = ab[o], bb = ab[256 + o];
        size_t p = (size_t)(b * NPTS + n) * 256 + o;
        float v = (a >= 0.f) ? ymax[p] : ymin[p];
        sm[(y + rr * 8) * 33 + x] = fmaxf(fmaf(v, a, bb), 0.f);
    }
    __syncthreads();
    #pragma unroll
    for (int rr = 0; rr < 4; rr++)
        out[((size_t)(b * 256 + o0 + y + rr * 8)) * NPTS + n0 + x] = sm[x * 33 + (y + rr * 8)];
}

extern "C" void kernel_launch(void* const* d_in, const int* in_sizes, int n_in,
                              void* d_out, int out_size, void* d_ws, size_t ws_size,
                              hipStream_t stream) {
    const float* xyz    = (const float*)d_in[0];
    const float* feat   = (const float*)d_in[1];
    const float* rot    = (const float*)d_in[2];
    const float* W1     = (const float*)d_in[3];
    const float* gamma1 = (const float*)d_in[4];
    const float* beta1  = (const float*)d_in[5];
    const float* W2     = (const float*)d_in[6];
    const float* gamma2 = (const float*)d_in[7];
    const float* beta2  = (const float*)d_in[8];
    float* out = (float*)d_out;

    char* ws = (char*)d_ws;
    u16*   featT = (u16*)(ws + 0);           //  4,194,304
    int*   idxp  = (int*)(ws + 4194304);     //  1,048,576
    u16*   gxyz  = (u16*)(ws + 5242880);     //  2,097,152
    u16*   Wp1   = (u16*)(ws + 7340032);     //    147,456
    u16*   Wp2   = (u16*)(ws + 7487488);     //    131,072
    float* ab1   = (float*)(ws + 7618560);   //      2,048
    float* ab2   = (float*)(ws + 7620608);   //      2,048
    float* Sacc  = (float*)(ws + 7753728);   //      1,024  (contiguous with Qacc/Xacc)
    float* Qacc  = (float*)(ws + 7754752);   //      1,024
    float* Xacc  = (float*)(ws + 7755776);   //      1,024
    float* xst64 = (float*)(ws + 7756800);   //      4,096  (64 x 9 used)
    float* hpart = (float*)(ws + 7760896);   //  2,097,152  (64 x 8192 f32)
    float* psum  = (float*)(ws + 9858048);   //  4,194,304
    float* psq   = (float*)(ws + 14052352);  //  4,194,304
    float* ymax  = (float*)(ws + 18246656);  //  8,388,608
    float* ymin  = (float*)(ws + 26635264);  //  8,388,608
    const size_t NEED = 35023872ull;

    // stage-2 reduction scratch (borrowed dead regions):
    //  - stats1 reduce (fallback) runs before pass 2 writes ymin -> borrow ymin
    //  - stats2 reduce runs after gxyz last use -> borrow gxyz
    float* r1s = (float*)(ws + 26635264);
    float* r1q = r1s + 16384;
    float* r2s = (float*)(ws + 5242880);
    float* r2q = r2s + 16384;

    query_k<<<2048, 256, 0, stream>>>(xyz, rot, idxp, gxyz, W1, W2, Wp1, Wp2);
    featT_k<<<dim3(64, 8, 4), 256, 0, stream>>>(feat, featT);

    if (ws_size >= NEED) {
        // stats1 via Gram decomposition over the 8192 unique gathered rows (no y1 materialization)
        hist_k<<<64, 256, 0, stream>>>(idxp, gxyz, hpart, xst64, Sacc);
        zgemm_k<<<NROW / 64, 256, 0, stream>>>(featT, Wp1, hpart, Sacc, Qacc, Xacc);
        ab1_k<<<1, 256, 0, stream>>>(Sacc, Qacc, Xacc, xst64, Wp1, gamma1, beta1, ab1);
        // single heavy pass: GEMM1 (reg-staged prefetch) -> norm1 (K-halved y1s) -> GEMM2 -> stats2+max/min
        fused_k<1><<<NBLK, 256, 0, stream>>>(featT, gxyz, idxp, Wp1, Wp2, ab1, psum, psq, ymax, ymin);
        reduce1_k<<<64, 256, 0, stream>>>(psum, psq, r2s, r2q);
        reduce2_k<<<1, 256, 0, stream>>>(r2s, r2q, gamma2, beta2, ab2);
    } else {
        // fallback: recompute GEMM1 in pass 2 (proven path)
        fused_k<0><<<NBLK, 256, 0, stream>>>(featT, gxyz, idxp, Wp1, Wp2, ab1, psum, psq, ymax, ymin);
        reduce1_k<<<64, 256, 0, stream>>>(psum, psq, r1s, r1q);
        reduce2_k<<<1, 256, 0, stream>>>(r1s, r1q, gamma1, beta1, ab1);
        fused_k<1><<<NBLK, 256, 0, stream>>>(featT, gxyz, idxp, Wp1, Wp2, ab1, psum, psq, ymax, ymin);
        reduce1_k<<<64, 256, 0, stream>>>(psum, psq, r2s, r2q);
        reduce2_k<<<1, 256, 0, stream>>>(r2s, r2q, gamma2, beta2, ab2);
    }
    final_k<<<dim3(64, 8, 4), 256, 0, stream>>>(ymax, ymin, ab2, out);
}

// Round 9
// 246.407 us; speedup vs baseline: 1.8576x; 1.8576x over previous
//
#include <hip/hip_runtime.h>

typedef unsigned short u16;
typedef unsigned int u32;
typedef __attribute__((ext_vector_type(8))) short bf16x8;
typedef __attribute__((ext_vector_type(4))) float f32x4;

#define NPTS 2048
#define CFEAT 256
#define NS 32
#define MTOT 262144           // 4*2048*32
#define NBLK 4096             // MTOT/64 m-tiles
#define INV_N (1.0f/262144.0f)

__device__ __forceinline__ float bf2f(u16 u) {
    union { u32 i; float f; } v; v.i = ((u32)u) << 16; return v.f;
}
__device__ __forceinline__ u16 f2bf(float f) {
    union { float f; u32 i; } v; v.f = f;
    u32 i = v.i;
    return (u16)((i + 0x7fffu + ((i >> 16) & 1u)) >> 16);
}

// async global->LDS, 16B per lane. LDS dest = wave-uniform base + lane*16; global src per-lane.
__device__ __forceinline__ void gload16(const void* g, void* l) {
    __builtin_amdgcn_global_load_lds((const __attribute__((address_space(1))) void*)g,
                                     (__attribute__((address_space(3))) void*)l, 16, 0, 0);
}

// ---------------- cylinder query + fused gxyz + folded W-prep (blocks 0..255) ----------------
__global__ __launch_bounds__(256) void query_k(const float* __restrict__ xyz, const float* __restrict__ rot,
                                               int* __restrict__ idx, u16* __restrict__ gxyz,
                                               const float* __restrict__ W1, const float* __restrict__ W2,
                                               u16* __restrict__ Wp1, u16* __restrict__ Wp2) {
    __shared__ int sidx[4 * NS];
    // folded prep: pack W1 -> [feat(256)|xyz(3)|0(29)] (K=288), W2 (K=256), bf16
    if (blockIdx.x < 256) {
        int o = blockIdx.x, t = threadIdx.x;
        Wp1[o * 288 + t] = f2bf(W1[o * 259 + 3 + t]);
        if (t < 32) Wp1[o * 288 + 256 + t] = (t < 3) ? f2bf(W1[o * 259 + t]) : (u16)0;
        Wp2[o * 256 + t] = f2bf(W2[o * 256 + t]);
    }
    const int wid = threadIdx.x >> 6;
    const int pid = blockIdx.x * 4 + wid;
    const int lane = threadIdx.x & 63;
    const int b = pid >> 11, p = pid & 2047;
    const float* xb = xyz + (size_t)b * NPTS * 3;
    float px = xb[p * 3 + 0], py = xb[p * 3 + 1], pz = xb[p * 3 + 2];
    const float* rp = rot + (size_t)pid * 9;
    float r00 = rp[0], r01 = rp[1], r02 = rp[2];
    float r10 = rp[3], r11 = rp[4], r12 = rp[5];
    float r20 = rp[6], r21 = rp[7], r22 = rp[8];
    int cnt = 0, first = 0;
    for (int n0 = 0; n0 < NPTS && cnt < NS; n0 += 64) {
        int n = n0 + lane;
        // exact fp32, sequential order, no fma contraction -> match numpy mask bitwise
        float dx = __fsub_rn(xb[n * 3 + 0], px);
        float dy = __fsub_rn(xb[n * 3 + 1], py);
        float dz = __fsub_rn(xb[n * 3 + 2], pz);
        float a0 = __fadd_rn(__fadd_rn(__fmul_rn(r00, dx), __fmul_rn(r01, dy)), __fmul_rn(r02, dz));
        float a1 = __fadd_rn(__fadd_rn(__fmul_rn(r10, dx), __fmul_rn(r11, dy)), __fmul_rn(r12, dz));
        float a2 = __fadd_rn(__fadd_rn(__fmul_rn(r20, dx), __fmul_rn(r21, dy)), __fmul_rn(r22, dz));
        float t2 = __fadd_rn(__fmul_rn(a1, a1), __fmul_rn(a2, a2));
        bool valid = (t2 < 0.0025f) && (a0 > -0.02f) && (a0 < 0.04f);
        unsigned long long bal = __ballot(valid);
        if (cnt == 0 && bal) first = n0 + __builtin_ctzll(bal);
        int rank = __builtin_popcountll(bal & ((1ull << lane) - 1ull));
        int slot = cnt + rank;
        if (valid && slot < NS) sidx[wid * NS + slot] = n;
        cnt += __builtin_popcountll(bal);
    }
    int filled = cnt < NS ? cnt : NS;
    __syncthreads();   // sidx visible
    if (lane < NS) {
        int i = (lane < filled) ? sidx[wid * NS + lane] : (cnt > 0 ? first : 0);
        idx[(size_t)pid * NS + lane] = i;
        // gxyz: rotated, scaled neighbor offset (same math as standalone gxyz_k)
        float dx = (xb[i * 3 + 0] - px) * 20.0f;
        float dy = (xb[i * 3 + 1] - py) * 20.0f;
        float dz = (xb[i * 3 + 2] - pz) * 20.0f;
        float g0 = dx * r00 + dy * r10 + dz * r20;
        float g1 = dx * r01 + dy * r11 + dz * r21;
        float g2 = dx * r02 + dy * r12 + dz * r22;
        uint2 v;
        v.x = (u32)f2bf(g0) | ((u32)f2bf(g1) << 16);
        v.y = (u32)f2bf(g2);
        *(uint2*)(gxyz + ((size_t)pid * NS + lane) * 4) = v;
    }
}

// ---------------- features (B,C,N) fp32 -> featT (B,N,C) bf16 ----------------
__global__ __launch_bounds__(256) void featT_k(const float* __restrict__ feat, u16* __restrict__ featT) {
    __shared__ float sm[32 * 33];
    int b = blockIdx.z;
    int n0 = blockIdx.x * 32, c0 = blockIdx.y * 32;
    int t = threadIdx.x, x = t & 31, y = t >> 5;
    #pragma unroll
    for (int rr = 0; rr < 4; rr++) {
        int c = c0 + y + rr * 8;
        sm[(y + rr * 8) * 33 + x] = feat[((size_t)(b * CFEAT + c)) * NPTS + n0 + x];
    }
    __syncthreads();
    #pragma unroll
    for (int rr = 0; rr < 4; rr++) {
        int n = n0 + y + rr * 8;
        featT[((size_t)(b * NPTS + n)) * CFEAT + c0 + x] = f2bf(sm[x * 33 + (y + rr * 8)]);
    }
}

// ---------------- fused GEMM1 (+optional norm1+GEMM2) over one 64-row m-tile (r1-proven) ----------
// FULL=0: stats1 partials (+y1 fragment spill when STORE=1).
// FULL=1: recompute GEMM1, norm1+relu -> LDS -> GEMM2 -> stats2 + y2 max/min (fallback path).
template <int FULL, int STORE>
__global__ __launch_bounds__(256) void fused_k(
    const u16* __restrict__ featT, const u16* __restrict__ gxyz, const int* __restrict__ idx,
    const u16* __restrict__ Wp1, const u16* __restrict__ Wp2, const float* __restrict__ ab1,
    float* __restrict__ psum, float* __restrict__ psq,
    float* __restrict__ ymax, float* __restrict__ ymin, uint2* __restrict__ y1f)
{
    __shared__ __attribute__((aligned(16))) u16 As[64 * 32];     // 4 KB
    __shared__ __attribute__((aligned(16))) u16 Bs[256 * 32];    // 16 KB
    __shared__ __attribute__((aligned(16))) u16 y1s[FULL ? 64 * 264 : 16];
    __shared__ int rowbase_s[64];

    const int tid = threadIdx.x;
    const int lane = tid & 63, wave = tid >> 6;
    const int quad = lane >> 4, tl = lane & 15;
    const int bx = blockIdx.x;
    const int m0 = bx * 64;

    if (tid < 64) {
        int m = m0 + tid;
        int gi = idx[m];
        int b = m >> 16;
        rowbase_s[tid] = (b * NPTS + gi) * CFEAT;
    }
    __syncthreads();
    const int srow = tid >> 2, sc16 = tid & 3;
    const int abase = rowbase_s[srow] + sc16 * 8;

    f32x4 acc[4][4];
    #pragma unroll
    for (int i = 0; i < 4; i++)
        #pragma unroll
        for (int j = 0; j < 4; j++) acc[i][j] = (f32x4){0.f, 0.f, 0.f, 0.f};

    auto mfma_tile = [&](f32x4 (&ac)[4][4], const u16* a_lds, int a_stride) {
        bf16x8 af[4], bv[4];
        #pragma unroll
        for (int i = 0; i < 4; i++) af[i] = *(const bf16x8*)(a_lds + (i * 16 + tl) * a_stride + quad * 8);
        #pragma unroll
        for (int j = 0; j < 4; j++) bv[j] = *(const bf16x8*)(Bs + (wave * 64 + j * 16 + tl) * 32 + quad * 8);
        #pragma unroll
        for (int i = 0; i < 4; i++)
            #pragma unroll
            for (int j = 0; j < 4; j++)
                ac[i][j] = __builtin_amdgcn_mfma_f32_16x16x32_bf16(af[i], bv[j], ac[i][j], 0, 0, 0);
    };

    // ---- GEMM1: K = 256 feat (gathered) + 1 xyz tile ----
    for (int ks = 0; ks < 8; ks++) {
        const int k0 = ks * 32;
        __syncthreads();
        gload16(featT + abase + k0, As + tid * 8);
        #pragma unroll
        for (int q = 0; q < 4; q++)
            gload16(Wp1 + (srow + q * 64) * 288 + k0 + sc16 * 8, Bs + q * 2048 + tid * 8);
        __syncthreads();
        mfma_tile(acc, As, 32);
    }
    {   // xyz K-tile
        __syncthreads();
        uint4 va = make_uint4(0, 0, 0, 0);
        if (sc16 == 0) {
            uint2 g2 = *(const uint2*)(gxyz + (size_t)(m0 + srow) * 4);
            va.x = g2.x; va.y = g2.y;
        }
        *(uint4*)(As + srow * 32 + sc16 * 8) = va;
        #pragma unroll
        for (int q = 0; q < 4; q++)
            gload16(Wp1 + (srow + q * 64) * 288 + 256 + sc16 * 8, Bs + q * 2048 + tid * 8);
        __syncthreads();
        mfma_tile(acc, As, 32);
    }

    if (!FULL) {
        #pragma unroll
        for (int j = 0; j < 4; j++) {
            float s = 0.f, q2 = 0.f;
            #pragma unroll
            for (int i = 0; i < 4; i++) {
                float v0 = acc[i][j][0], v1 = acc[i][j][1], v2 = acc[i][j][2], v3 = acc[i][j][3];
                if (STORE) {
                    u32 lo = (u32)f2bf(v0) | ((u32)f2bf(v1) << 16);
                    u32 hi = (u32)f2bf(v2) | ((u32)f2bf(v3) << 16);
                    y1f[((size_t)(bx * 4 + wave) * 16 + i * 4 + j) * 64 + lane] = make_uint2(lo, hi);
                    // stats on the rounded values for self-consistency with pass 2
                    v0 = bf2f((u16)(lo & 0xffff)); v1 = bf2f((u16)(lo >> 16));
                    v2 = bf2f((u16)(hi & 0xffff)); v3 = bf2f((u16)(hi >> 16));
                }
                s += v0 + v1 + v2 + v3;
                q2 += v0 * v0 + v1 * v1 + v2 * v2 + v3 * v3;
            }
            s += __shfl_xor(s, 16); s += __shfl_xor(s, 32);
            q2 += __shfl_xor(q2, 16); q2 += __shfl_xor(q2, 32);
            if (quad == 0) {
                int col = wave * 64 + j * 16 + tl;
                psum[(size_t)bx * 256 + col] = s;
                psq[(size_t)bx * 256 + col] = q2;
            }
        }
        return;
    }

    // ---- norm1 + relu -> y1s (bf16) ----
    #pragma unroll
    for (int j = 0; j < 4; j++) {
        int col = wave * 64 + j * 16 + tl;
        float a = ab1[col], bb = ab1[256 + col];
        #pragma unroll
        for (int i = 0; i < 4; i++)
            #pragma unroll
            for (int r = 0; r < 4; r++) {
                float v = fmaxf(fmaf(acc[i][j][r], a, bb), 0.f);
                y1s[(i * 16 + quad * 4 + r) * 264 + col] = f2bf(v);
            }
    }

    // ---- GEMM2 ----
    f32x4 acc2[4][4];
    #pragma unroll
    for (int i = 0; i < 4; i++)
        #pragma unroll
        for (int j = 0; j < 4; j++) acc2[i][j] = (f32x4){0.f, 0.f, 0.f, 0.f};
    for (int ks = 0; ks < 8; ks++) {
        const int k0 = ks * 32;
        __syncthreads();
        #pragma unroll
        for (int q = 0; q < 4; q++)
            gload16(Wp2 + (srow + q * 64) * 256 + k0 + sc16 * 8, Bs + q * 2048 + tid * 8);
        __syncthreads();
        mfma_tile(acc2, y1s + k0, 264);
    }

    // ---- epilogue2 ----
    #pragma unroll
    for (int j = 0; j < 4; j++) {
        int col = wave * 64 + j * 16 + tl;
        float s = 0.f, q2 = 0.f;
        float mx0 = -3.0e38f, mn0 = 3.0e38f, mx1 = -3.0e38f, mn1 = 3.0e38f;
        #pragma unroll
        for (int i = 0; i < 4; i++)
            #pragma unroll
            for (int r = 0; r < 4; r++) {
                float v = acc2[i][j][r];
                s += v; q2 += v * v;
                if (i < 2) { mx0 = fmaxf(mx0, v); mn0 = fminf(mn0, v); }
                else       { mx1 = fmaxf(mx1, v); mn1 = fminf(mn1, v); }
            }
        s += __shfl_xor(s, 16); s += __shfl_xor(s, 32);
        q2 += __shfl_xor(q2, 16); q2 += __shfl_xor(q2, 32);
        mx0 = fmaxf(mx0, __shfl_xor(mx0, 16)); mx0 = fmaxf(mx0, __shfl_xor(mx0, 32));
        mn0 = fminf(mn0, __shfl_xor(mn0, 16)); mn0 = fminf(mn0, __shfl_xor(mn0, 32));
        mx1 = fmaxf(mx1, __shfl_xor(mx1, 16)); mx1 = fmaxf(mx1, __shfl_xor(mx1, 32));
        mn1 = fminf(mn1, __shfl_xor(mn1, 16)); mn1 = fminf(mn1, __shfl_xor(mn1, 32));
        if (quad == 0) {
            psum[(size_t)bx * 256 + col] = s;
            psq[(size_t)bx * 256 + col] = q2;
            size_t p0 = (size_t)(bx * 2) * 256 + col;
            size_t p1 = (size_t)(bx * 2 + 1) * 256 + col;
            ymax[p0] = mx0; ymin[p0] = mn0;
            ymax[p1] = mx1; ymin[p1] = mn1;
        }
    }
}

// ---------------- pass 2 (big-ws path): reload y1 frags, norm+relu -> LDS -> GEMM2 (r1-proven) ------
__global__ __launch_bounds__(256) void fused2_k(
    const uint2* __restrict__ y1f, const u16* __restrict__ Wp2, const float* __restrict__ ab1,
    float* __restrict__ psum, float* __restrict__ psq,
    float* __restrict__ ymax, float* __restrict__ ymin)
{
    __shared__ __attribute__((aligned(16))) u16 Bs[256 * 32];    // 16 KB
    __shared__ __attribute__((aligned(16))) u16 y1s[64 * 264];   // 33.8 KB -> 3 blocks/CU
    const int tid = threadIdx.x;
    const int lane = tid & 63, wave = tid >> 6;
    const int quad = lane >> 4, tl = lane & 15;
    const int bx = blockIdx.x;

    // reload this lane's own pass-1 fragments (coalesced), normalize, deposit to LDS
    #pragma unroll
    for (int j = 0; j < 4; j++) {
        int col = wave * 64 + j * 16 + tl;
        float a = ab1[col], bb = ab1[256 + col];
        #pragma unroll
        for (int i = 0; i < 4; i++) {
            uint2 v = y1f[((size_t)(bx * 4 + wave) * 16 + i * 4 + j) * 64 + lane];
            float f0 = bf2f((u16)(v.x & 0xffff)), f1 = bf2f((u16)(v.x >> 16));
            float f2 = bf2f((u16)(v.y & 0xffff)), f3 = bf2f((u16)(v.y >> 16));
            int rb = (i * 16 + quad * 4) * 264 + col;
            y1s[rb] = f2bf(fmaxf(fmaf(f0, a, bb), 0.f));
            y1s[rb + 264] = f2bf(fmaxf(fmaf(f1, a, bb), 0.f));
            y1s[rb + 528] = f2bf(fmaxf(fmaf(f2, a, bb), 0.f));
            y1s[rb + 792] = f2bf(fmaxf(fmaf(f3, a, bb), 0.f));
        }
    }

    const int srow = tid >> 2, sc16 = tid & 3;
    f32x4 acc2[4][4];
    #pragma unroll
    for (int i = 0; i < 4; i++)
        #pragma unroll
        for (int j = 0; j < 4; j++) acc2[i][j] = (f32x4){0.f, 0.f, 0.f, 0.f};

    for (int ks = 0; ks < 8; ks++) {
        const int k0 = ks * 32;
        __syncthreads();   // first iter: covers y1s writes
        #pragma unroll
        for (int q = 0; q < 4; q++)
            gload16(Wp2 + (srow + q * 64) * 256 + k0 + sc16 * 8, Bs + q * 2048 + tid * 8);
        __syncthreads();
        bf16x8 af[4], bv[4];
        #pragma unroll
        for (int i = 0; i < 4; i++) af[i] = *(const bf16x8*)(y1s + (i * 16 + tl) * 264 + k0 + quad * 8);
        #pragma unroll
        for (int j = 0; j < 4; j++) bv[j] = *(const bf16x8*)(Bs + (wave * 64 + j * 16 + tl) * 32 + quad * 8);
        #pragma unroll
        for (int i = 0; i < 4; i++)
            #pragma unroll
            for (int j = 0; j < 4; j++)
                acc2[i][j] = __builtin_amdgcn_mfma_f32_16x16x32_bf16(af[i], bv[j], acc2[i][j], 0, 0, 0);
    }

    #pragma unroll
    for (int j = 0; j < 4; j++) {
        int col = wave * 64 + j * 16 + tl;
        float s = 0.f, q2 = 0.f;
        float mx0 = -3.0e38f, mn0 = 3.0e38f, mx1 = -3.0e38f, mn1 = 3.0e38f;
        #pragma unroll
        for (int i = 0; i < 4; i++)
            #pragma unroll
            for (int r = 0; r < 4; r++) {
                float v = acc2[i][j][r];
                s += v; q2 += v * v;
                if (i < 2) { mx0 = fmaxf(mx0, v); mn0 = fminf(mn0, v); }
                else       { mx1 = fmaxf(mx1, v); mn1 = fminf(mn1, v); }
            }
        s += __shfl_xor(s, 16); s += __shfl_xor(s, 32);
        q2 += __shfl_xor(q2, 16); q2 += __shfl_xor(q2, 32);
        mx0 = fmaxf(mx0, __shfl_xor(mx0, 16)); mx0 = fmaxf(mx0, __shfl_xor(mx0, 32));
        mn0 = fminf(mn0, __shfl_xor(mn0, 16)); mn0 = fminf(mn0, __shfl_xor(mn0, 32));
        mx1 = fmaxf(mx1, __shfl_xor(mx1, 16)); mx1 = fmaxf(mx1, __shfl_xor(mx1, 32));
        mn1 = fminf(mn1, __shfl_xor(mn1, 16)); mn1 = fminf(mn1, __shfl_xor(mn1, 32));
        if (quad == 0) {
            psum[(size_t)bx * 256 + col] = s;
            psq[(size_t)bx * 256 + col] = q2;
            size_t p0 = (size_t)(bx * 2) * 256 + col;
            size_t p1 = (size_t)(bx * 2 + 1) * 256 + col;
            ymax[p0] = mx0; ymin[p0] = mn0;
            ymax[p1] = mx1; ymin[p1] = mn1;
        }
    }
}

// ---------------- stats reduction: 64 blocks x 64 rows (coalesced), then 1-block 64-iter finish ------
__global__ __launch_bounds__(256) void reduce1_k(const float* __restrict__ psum, const float* __restrict__ psq,
                                                 float* __restrict__ ps2, float* __restrict__ pq2) {
    int j = blockIdx.x, t = threadIdx.x;
    float s = 0.f, q = 0.f;
    #pragma unroll 4
    for (int kk = 0; kk < 64; kk++) {
        size_t r = (size_t)(j * 64 + kk) * 256 + t;
        s += psum[r]; q += psq[r];
    }
    ps2[j * 256 + t] = s;
    pq2[j * 256 + t] = q;
}

__global__ __launch_bounds__(256) void reduce2_k(const float* __restrict__ ps2, const float* __restrict__ pq2,
                                                 const float* __restrict__ gamma, const float* __restrict__ beta,
                                                 float* __restrict__ ab) {
    int c = threadIdx.x;
    float S = 0.f, Q = 0.f;
    for (int j = 0; j < 64; j++) {
        S += ps2[j * 256 + c];
        Q += pq2[j * 256 + c];
    }
    float mu = S * INV_N;
    float var = Q * INV_N - mu * mu;
    float a = gamma[c] * rsqrtf(var + 1e-5f);
    ab[c] = a;
    ab[256 + c] = beta[c] - mu * a;
}

// ---------------- final: relu(a*(a>=0?max:min)+b), transpose -> (B,O,N) ----------------
__global__ __launch_bounds__(256) void final_k(const float* __restrict__ ymax, const float* __restrict__ ymin,
                                               const float* __restrict__ ab, float* __restrict__ out) {
    __shared__ float sm[32 * 33];
    int b = blockIdx.z;
    int n0 = blockIdx.x * 32, o0 = blockIdx.y * 32;
    int t = threadIdx.x, x = t & 31, y = t >> 5;
    #pragma unroll
    for (int rr = 0; rr < 4; rr++) {
        int n = n0 + y + rr * 8;
        int o = o0 + x;
        float a = ab[o], bb = ab[256 + o];
        size_t p = (size_t)(b * NPTS + n) * 256 + o;
        float v = (a >= 0.f) ? ymax[p] : ymin[p];
        sm[(y + rr * 8) * 33 + x] = fmaxf(fmaf(v, a, bb), 0.f);
    }
    __syncthreads();
    #pragma unroll
    for (int rr = 0; rr < 4; rr++)
        out[((size_t)(b * 256 + o0 + y + rr * 8)) * NPTS + n0 + x] = sm[x * 33 + (y + rr * 8)];
}

extern "C" void kernel_launch(void* const* d_in, const int* in_sizes, int n_in,
                              void* d_out, int out_size, void* d_ws, size_t ws_size,
                              hipStream_t stream) {
    const float* xyz    = (const float*)d_in[0];
    const float* feat   = (const float*)d_in[1];
    const float* rot    = (const float*)d_in[2];
    const float* W1     = (const float*)d_in[3];
    const float* gamma1 = (const float*)d_in[4];
    const float* beta1  = (const float*)d_in[5];
    const float* W2     = (const float*)d_in[6];
    const float* gamma2 = (const float*)d_in[7];
    const float* beta2  = (const float*)d_in[8];
    float* out = (float*)d_out;

    char* ws = (char*)d_ws;
    u16*   featT = (u16*)(ws + 0);           //  4,194,304
    int*   idxp  = (int*)(ws + 4194304);     //  1,048,576
    u16*   gxyz  = (u16*)(ws + 5242880);     //  2,097,152
    u16*   Wp1   = (u16*)(ws + 7340032);     //    147,456
    u16*   Wp2   = (u16*)(ws + 7487488);     //    131,072
    float* ab1   = (float*)(ws + 7618560);   //      2,048
    float* ab2   = (float*)(ws + 7620608);   //      2,048
    float* psum  = (float*)(ws + 7622656);   //  4,194,304
    float* psq   = (float*)(ws + 11816960);  //  4,194,304
    float* ymax  = (float*)(ws + 16011264);  //  8,388,608
    float* ymin  = (float*)(ws + 24399872);  //  8,388,608
    uint2* y1f   = (uint2*)(ws + 32788480);  // 134,217,728 (big path only)
    const size_t BIG_NEED = 32788480ull + 134217728ull;   // 167,006,208

    // stage-2 reduction scratch (64x256 f32 each), borrowed dead regions:
    //  - stats1 reduce runs before pass 2 writes ymin -> borrow ymin region
    //  - stats2 reduce runs after gxyz last use -> borrow gxyz region
    float* r1s = (float*)(ws + 24399872);
    float* r1q = r1s + 16384;
    float* r2s = (float*)(ws + 5242880);
    float* r2q = r2s + 16384;

    query_k<<<2048, 256, 0, stream>>>(xyz, rot, idxp, gxyz, W1, W2, Wp1, Wp2);
    featT_k<<<dim3(64, 8, 4), 256, 0, stream>>>(feat, featT);

    if (ws_size >= BIG_NEED) {
        // pass 1: GEMM1 + fragment-layout y1 spill + stats1
        fused_k<0, 1><<<NBLK, 256, 0, stream>>>(featT, gxyz, idxp, Wp1, Wp2, ab1, psum, psq, ymax, ymin, y1f);
        reduce1_k<<<64, 256, 0, stream>>>(psum, psq, r1s, r1q);
        reduce2_k<<<1, 256, 0, stream>>>(r1s, r1q, gamma1, beta1, ab1);
        // pass 2: reload y1 frags -> norm/relu -> GEMM2 + stats2 + max/min
        fused2_k<<<NBLK, 256, 0, stream>>>(y1f, Wp2, ab1, psum, psq, ymax, ymin);
        reduce1_k<<<64, 256, 0, stream>>>(psum, psq, r2s, r2q);
        reduce2_k<<<1, 256, 0, stream>>>(r2s, r2q, gamma2, beta2, ab2);
    } else {
        // fallback: recompute GEMM1 in pass 2 (proven path)
        fused_k<0, 0><<<NBLK, 256, 0, stream>>>(featT, gxyz, idxp, Wp1, Wp2, ab1, psum, psq, ymax, ymin, nullptr);
        reduce1_k<<<64, 256, 0, stream>>>(psum, psq, r1s, r1q);
        reduce2_k<<<1, 256, 0, stream>>>(r1s, r1q, gamma1, beta1, ab1);
        fused_k<1, 0><<<NBLK, 256, 0, stream>>>(featT, gxyz, idxp, Wp1, Wp2, ab1, psum, psq, ymax, ymin, nullptr);
        reduce1_k<<<64, 256, 0, stream>>>(psum, psq, r2s, r2q);
        reduce2_k<<<1, 256, 0, stream>>>(r2s, r2q, gamma2, beta2, ab2);
    }
    final_k<<<dim3(64, 8, 4), 256, 0, stream>>>(ymax, ymin, ab2, out);
}

// Round 10
// 232.042 us; speedup vs baseline: 1.9726x; 1.0619x over previous
//
#include <hip/hip_runtime.h>

typedef unsigned short u16;
typedef unsigned int u32;
typedef __attribute__((ext_vector_type(8))) short bf16x8;
typedef __attribute__((ext_vector_type(4))) float f32x4;

#define NPTS 2048
#define CFEAT 256
#define NS 32
#define MTOT 262144           // 4*2048*32
#define NBLK 4096             // MTOT/64 m-tiles
#define INV_N (1.0f/262144.0f)

__device__ __forceinline__ float bf2f(u16 u) {
    union { u32 i; float f; } v; v.i = ((u32)u) << 16; return v.f;
}
__device__ __forceinline__ u16 f2bf(float f) {
    union { float f; u32 i; } v; v.f = f;
    u32 i = v.i;
    return (u16)((i + 0x7fffu + ((i >> 16) & 1u)) >> 16);
}

// async global->LDS, 16B per lane. LDS dest = wave-uniform base + lane*16; global src per-lane.
__device__ __forceinline__ void gload16(const void* g, void* l) {
    __builtin_amdgcn_global_load_lds((const __attribute__((address_space(1))) void*)g,
                                     (__attribute__((address_space(3))) void*)l, 16, 0, 0);
}

// ---------------- cylinder query + gxyz + folded W-prep (blocks 0..255) + folded featT tile ----------
__global__ __launch_bounds__(256) void query_k(const float* __restrict__ xyz, const float* __restrict__ rot,
                                               const float* __restrict__ feat,
                                               int* __restrict__ idx, u16* __restrict__ gxyz,
                                               u16* __restrict__ featT,
                                               const float* __restrict__ W1, const float* __restrict__ W2,
                                               u16* __restrict__ Wp1, u16* __restrict__ Wp2) {
    __shared__ float sm[32 * 33];
    __shared__ int sidx[4 * NS];
    const int tid = threadIdx.x;
    // folded prep: pack W1 -> [feat(256)|xyz(3)|0(29)] (K=288), W2 (K=256), bf16
    if (blockIdx.x < 256) {
        int o = blockIdx.x;
        Wp1[o * 288 + tid] = f2bf(W1[o * 259 + 3 + tid]);
        if (tid < 32) Wp1[o * 288 + 256 + tid] = (tid < 3) ? f2bf(W1[o * 259 + tid]) : (u16)0;
        Wp2[o * 256 + tid] = f2bf(W2[o * 256 + tid]);
    }
    // folded featT tile: (B,C,N) fp32 -> (B,N,C) bf16, old grid (64,8,4) linearized
    {
        int bb = blockIdx.x >> 9;
        int c0 = ((blockIdx.x >> 6) & 7) * 32;
        int n0 = (blockIdx.x & 63) * 32;
        int x = tid & 31, y = tid >> 5;
        #pragma unroll
        for (int rr = 0; rr < 4; rr++) {
            int c = c0 + y + rr * 8;
            sm[(y + rr * 8) * 33 + x] = feat[((size_t)(bb * CFEAT + c)) * NPTS + n0 + x];
        }
        __syncthreads();
        #pragma unroll
        for (int rr = 0; rr < 4; rr++) {
            int n = n0 + y + rr * 8;
            featT[((size_t)(bb * NPTS + n)) * CFEAT + c0 + x] = f2bf(sm[x * 33 + (y + rr * 8)]);
        }
    }
    // cylinder query (wave per point) + gxyz emit
    const int wid = tid >> 6;
    const int pid = blockIdx.x * 4 + wid;
    const int lane = tid & 63;
    const int b = pid >> 11, p = pid & 2047;
    const float* xb = xyz + (size_t)b * NPTS * 3;
    float px = xb[p * 3 + 0], py = xb[p * 3 + 1], pz = xb[p * 3 + 2];
    const float* rp = rot + (size_t)pid * 9;
    float r00 = rp[0], r01 = rp[1], r02 = rp[2];
    float r10 = rp[3], r11 = rp[4], r12 = rp[5];
    float r20 = rp[6], r21 = rp[7], r22 = rp[8];
    int cnt = 0, first = 0;
    for (int n0 = 0; n0 < NPTS && cnt < NS; n0 += 64) {
        int n = n0 + lane;
        // exact fp32, sequential order, no fma contraction -> match numpy mask bitwise
        float dx = __fsub_rn(xb[n * 3 + 0], px);
        float dy = __fsub_rn(xb[n * 3 + 1], py);
        float dz = __fsub_rn(xb[n * 3 + 2], pz);
        float a0 = __fadd_rn(__fadd_rn(__fmul_rn(r00, dx), __fmul_rn(r01, dy)), __fmul_rn(r02, dz));
        float a1 = __fadd_rn(__fadd_rn(__fmul_rn(r10, dx), __fmul_rn(r11, dy)), __fmul_rn(r12, dz));
        float a2 = __fadd_rn(__fadd_rn(__fmul_rn(r20, dx), __fmul_rn(r21, dy)), __fmul_rn(r22, dz));
        float t2 = __fadd_rn(__fmul_rn(a1, a1), __fmul_rn(a2, a2));
        bool valid = (t2 < 0.0025f) && (a0 > -0.02f) && (a0 < 0.04f);
        unsigned long long bal = __ballot(valid);
        if (cnt == 0 && bal) first = n0 + __builtin_ctzll(bal);
        int rank = __builtin_popcountll(bal & ((1ull << lane) - 1ull));
        int slot = cnt + rank;
        if (valid && slot < NS) sidx[wid * NS + slot] = n;
        cnt += __builtin_popcountll(bal);
    }
    int filled = cnt < NS ? cnt : NS;
    __syncthreads();   // sidx visible
    if (lane < NS) {
        int i = (lane < filled) ? sidx[wid * NS + lane] : (cnt > 0 ? first : 0);
        idx[(size_t)pid * NS + lane] = i;
        float dx = (xb[i * 3 + 0] - px) * 20.0f;
        float dy = (xb[i * 3 + 1] - py) * 20.0f;
        float dz = (xb[i * 3 + 2] - pz) * 20.0f;
        float g0 = dx * r00 + dy * r10 + dz * r20;
        float g1 = dx * r01 + dy * r11 + dz * r21;
        float g2 = dx * r02 + dy * r12 + dz * r22;
        uint2 v;
        v.x = (u32)f2bf(g0) | ((u32)f2bf(g1) << 16);
        v.y = (u32)f2bf(g2);
        *(uint2*)(gxyz + ((size_t)pid * NS + lane) * 4) = v;
    }
}

// ---------------- fused GEMM1 (+optional norm1+GEMM2) over one 64-row m-tile ----------------
// GEMM1 now BK=64: 4 feat phases + 1 xyz phase (was 9). Stride-64 LDS rows are a 16-way bank
// conflict, so staging pre-swizzles the GLOBAL source slot (linear LDS dest, rule m173) and the
// MFMA reads apply the same XOR: slot' = slot ^ (row&7). K-accumulation order identical to r9.
// FULL=0: stats1 partials (+y1 fragment spill when STORE=1).
// FULL=1: recompute GEMM1, norm1+relu -> LDS -> GEMM2 (fallback path, BK=32 GEMM2 unchanged).
template <int FULL, int STORE>
__global__ __launch_bounds__(256) void fused_k(
    const u16* __restrict__ featT, const u16* __restrict__ gxyz, const int* __restrict__ idx,
    const u16* __restrict__ Wp1, const u16* __restrict__ Wp2, const float* __restrict__ ab1,
    float* __restrict__ psum, float* __restrict__ psq,
    float* __restrict__ ymax, float* __restrict__ ymin, uint2* __restrict__ y1f)
{
    __shared__ __attribute__((aligned(16))) u16 As[64 * 64];     //  8 KB
    __shared__ __attribute__((aligned(16))) u16 Bs[256 * 64];    // 32 KB
    __shared__ __attribute__((aligned(16))) u16 y1s[FULL ? 64 * 264 : 16];
    __shared__ int rowbase_s[64];

    const int tid = threadIdx.x;
    const int lane = tid & 63, wave = tid >> 6;
    const int quad = lane >> 4, tl = lane & 15;
    const int bx = blockIdx.x;
    const int m0 = bx * 64;

    if (tid < 64) {
        int m = m0 + tid;
        int gi = idx[m];
        int b = m >> 16;
        rowbase_s[tid] = (b * NPTS + gi) * CFEAT;
    }
    __syncthreads();

    // staging geometry: thread covers (row = tid>>3 [+32], dest slot = tid&7); source slot
    // pre-swizzled so that LDS ends up holding slot s at position s^(row&7).
    const int sr8 = tid >> 3;                 // 0..31
    const int koffA = (((tid & 7) ^ (sr8 & 7)) * 8);   // (sr8+32)&7 == sr8&7

    f32x4 acc[4][4];
    #pragma unroll
    for (int i = 0; i < 4; i++)
        #pragma unroll
        for (int j = 0; j < 4; j++) acc[i][j] = (f32x4){0.f, 0.f, 0.f, 0.f};

    // ---- GEMM1: 4 feat phases (BK=64) ----
    for (int t = 0; t < 4; t++) {
        const int k0 = t * 64;
        __syncthreads();
        gload16(featT + rowbase_s[sr8] + k0 + koffA, As + tid * 8);
        gload16(featT + rowbase_s[sr8 + 32] + k0 + koffA, As + 2048 + tid * 8);
        #pragma unroll
        for (int c = 0; c < 8; c++)
            gload16(Wp1 + (c * 32 + sr8) * 288 + k0 + koffA, Bs + c * 2048 + tid * 8);
        __syncthreads();   // vmcnt(0) drain: tiles landed
        #pragma unroll
        for (int kk = 0; kk < 2; kk++) {
            bf16x8 af[4], bv[4];
            #pragma unroll
            for (int i = 0; i < 4; i++)
                af[i] = *(const bf16x8*)(As + (i * 16 + tl) * 64 + (((kk * 4 + quad) ^ (tl & 7)) * 8));
            #pragma unroll
            for (int j = 0; j < 4; j++)
                bv[j] = *(const bf16x8*)(Bs + (wave * 64 + j * 16 + tl) * 64 + (((kk * 4 + quad) ^ (tl & 7)) * 8));
            #pragma unroll
            for (int i = 0; i < 4; i++)
                #pragma unroll
                for (int j = 0; j < 4; j++)
                    acc[i][j] = __builtin_amdgcn_mfma_f32_16x16x32_bf16(af[i], bv[j], acc[i][j], 0, 0, 0);
        }
    }
    // ---- xyz phase (K=32, register-staged with swizzled ds_write) ----
    {
        __syncthreads();
        const int srow = tid >> 2, sc16 = tid & 3;
        uint4 va = make_uint4(0, 0, 0, 0);
        if (sc16 == 0) {
            uint2 g2 = *(const uint2*)(gxyz + (size_t)(m0 + srow) * 4);
            va.x = g2.x; va.y = g2.y;
        }
        *(uint4*)(As + srow * 64 + ((sc16 ^ (srow & 7)) * 8)) = va;
        #pragma unroll
        for (int s = 0; s < 4; s++) {
            uint4 w = *(const uint4*)(Wp1 + tid * 288 + 256 + s * 8);
            *(uint4*)(Bs + tid * 64 + ((s ^ (tid & 7)) * 8)) = w;
        }
        __syncthreads();
        bf16x8 af[4], bv[4];
        #pragma unroll
        for (int i = 0; i < 4; i++)
            af[i] = *(const bf16x8*)(As + (i * 16 + tl) * 64 + ((quad ^ (tl & 7)) * 8));
        #pragma unroll
        for (int j = 0; j < 4; j++)
            bv[j] = *(const bf16x8*)(Bs + (wave * 64 + j * 16 + tl) * 64 + ((quad ^ (tl & 7)) * 8));
        #pragma unroll
        for (int i = 0; i < 4; i++)
            #pragma unroll
            for (int j = 0; j < 4; j++)
                acc[i][j] = __builtin_amdgcn_mfma_f32_16x16x32_bf16(af[i], bv[j], acc[i][j], 0, 0, 0);
    }

    if (!FULL) {
        #pragma unroll
        for (int j = 0; j < 4; j++) {
            float s = 0.f, q2 = 0.f;
            #pragma unroll
            for (int i = 0; i < 4; i++) {
                float v0 = acc[i][j][0], v1 = acc[i][j][1], v2 = acc[i][j][2], v3 = acc[i][j][3];
                if (STORE) {
                    u32 lo = (u32)f2bf(v0) | ((u32)f2bf(v1) << 16);
                    u32 hi = (u32)f2bf(v2) | ((u32)f2bf(v3) << 16);
                    y1f[((size_t)(bx * 4 + wave) * 16 + i * 4 + j) * 64 + lane] = make_uint2(lo, hi);
                    // stats on the rounded values for self-consistency with pass 2
                    v0 = bf2f((u16)(lo & 0xffff)); v1 = bf2f((u16)(lo >> 16));
                    v2 = bf2f((u16)(hi & 0xffff)); v3 = bf2f((u16)(hi >> 16));
                }
                s += v0 + v1 + v2 + v3;
                q2 += v0 * v0 + v1 * v1 + v2 * v2 + v3 * v3;
            }
            s += __shfl_xor(s, 16); s += __shfl_xor(s, 32);
            q2 += __shfl_xor(q2, 16); q2 += __shfl_xor(q2, 32);
            if (quad == 0) {
                int col = wave * 64 + j * 16 + tl;
                psum[(size_t)bx * 256 + col] = s;
                psq[(size_t)bx * 256 + col] = q2;
            }
        }
        return;
    }

    // ---- norm1 + relu -> y1s (bf16) ----
    #pragma unroll
    for (int j = 0; j < 4; j++) {
        int col = wave * 64 + j * 16 + tl;
        float a = ab1[col], bb = ab1[256 + col];
        #pragma unroll
        for (int i = 0; i < 4; i++)
            #pragma unroll
            for (int r = 0; r < 4; r++) {
                float v = fmaxf(fmaf(acc[i][j][r], a, bb), 0.f);
                y1s[(i * 16 + quad * 4 + r) * 264 + col] = f2bf(v);
            }
    }

    // ---- GEMM2 (BK=32, unchanged; reuses first 16KB of Bs with stride-32 mapping) ----
    const int srow = tid >> 2, sc16 = tid & 3;
    f32x4 acc2[4][4];
    #pragma unroll
    for (int i = 0; i < 4; i++)
        #pragma unroll
        for (int j = 0; j < 4; j++) acc2[i][j] = (f32x4){0.f, 0.f, 0.f, 0.f};
    for (int ks = 0; ks < 8; ks++) {
        const int k0 = ks * 32;
        __syncthreads();
        #pragma unroll
        for (int q = 0; q < 4; q++)
            gload16(Wp2 + (srow + q * 64) * 256 + k0 + sc16 * 8, Bs + q * 2048 + tid * 8);
        __syncthreads();
        bf16x8 af[4], bv[4];
        #pragma unroll
        for (int i = 0; i < 4; i++) af[i] = *(const bf16x8*)(y1s + (i * 16 + tl) * 264 + k0 + quad * 8);
        #pragma unroll
        for (int j = 0; j < 4; j++) bv[j] = *(const bf16x8*)(Bs + (wave * 64 + j * 16 + tl) * 32 + quad * 8);
        #pragma unroll
        for (int i = 0; i < 4; i++)
            #pragma unroll
            for (int j = 0; j < 4; j++)
                acc2[i][j] = __builtin_amdgcn_mfma_f32_16x16x32_bf16(af[i], bv[j], acc2[i][j], 0, 0, 0);
    }

    // ---- epilogue2 ----
    #pragma unroll
    for (int j = 0; j < 4; j++) {
        int col = wave * 64 + j * 16 + tl;
        float s = 0.f, q2 = 0.f;
        float mx0 = -3.0e38f, mn0 = 3.0e38f, mx1 = -3.0e38f, mn1 = 3.0e38f;
        #pragma unroll
        for (int i = 0; i < 4; i++)
            #pragma unroll
            for (int r = 0; r < 4; r++) {
                float v = acc2[i][j][r];
                s += v; q2 += v * v;
                if (i < 2) { mx0 = fmaxf(mx0, v); mn0 = fminf(mn0, v); }
                else       { mx1 = fmaxf(mx1, v); mn1 = fminf(mn1, v); }
            }
        s += __shfl_xor(s, 16); s += __shfl_xor(s, 32);
        q2 += __shfl_xor(q2, 16); q2 += __shfl_xor(q2, 32);
        mx0 = fmaxf(mx0, __shfl_xor(mx0, 16)); mx0 = fmaxf(mx0, __shfl_xor(mx0, 32));
        mn0 = fminf(mn0, __shfl_xor(mn0, 16)); mn0 = fminf(mn0, __shfl_xor(mn0, 32));
        mx1 = fmaxf(mx1, __shfl_xor(mx1, 16)); mx1 = fmaxf(mx1, __shfl_xor(mx1, 32));
        mn1 = fminf(mn1, __shfl_xor(mn1, 16)); mn1 = fminf(mn1, __shfl_xor(mn1, 32));
        if (quad == 0) {
            psum[(size_t)bx * 256 + col] = s;
            psq[(size_t)bx * 256 + col] = q2;
            size_t p0 = (size_t)(bx * 2) * 256 + col;
            size_t p1 = (size_t)(bx * 2 + 1) * 256 + col;
            ymax[p0] = mx0; ymin[p0] = mn0;
            ymax[p1] = mx1; ymin[p1] = mn1;
        }
    }
}

// ---------------- pass 2 (big-ws path): reload y1 frags, norm+relu -> LDS -> GEMM2 (r9-proven) ------
__global__ __launch_bounds__(256) void fused2_k(
    const uint2* __restrict__ y1f, const u16* __restrict__ Wp2, const float* __restrict__ ab1,
    float* __restrict__ psum, float* __restrict__ psq,
    float* __restrict__ ymax, float* __restrict__ ymin)
{
    __shared__ __attribute__((aligned(16))) u16 Bs[256 * 32];    // 16 KB
    __shared__ __attribute__((aligned(16))) u16 y1s[64 * 264];   // 33.8 KB -> 3 blocks/CU
    const int tid = threadIdx.x;
    const int lane = tid & 63, wave = tid >> 6;
    const int quad = lane >> 4, tl = lane & 15;
    const int bx = blockIdx.x;

    // reload this lane's own pass-1 fragments (coalesced), normalize, deposit to LDS
    #pragma unroll
    for (int j = 0; j < 4; j++) {
        int col = wave * 64 + j * 16 + tl;
        float a = ab1[col], bb = ab1[256 + col];
        #pragma unroll
        for (int i = 0; i < 4; i++) {
            uint2 v = y1f[((size_t)(bx * 4 + wave) * 16 + i * 4 + j) * 64 + lane];
            float f0 = bf2f((u16)(v.x & 0xffff)), f1 = bf2f((u16)(v.x >> 16));
            float f2 = bf2f((u16)(v.y & 0xffff)), f3 = bf2f((u16)(v.y >> 16));
            int rb = (i * 16 + quad * 4) * 264 + col;
            y1s[rb] = f2bf(fmaxf(fmaf(f0, a, bb), 0.f));
            y1s[rb + 264] = f2bf(fmaxf(fmaf(f1, a, bb), 0.f));
            y1s[rb + 528] = f2bf(fmaxf(fmaf(f2, a, bb), 0.f));
            y1s[rb + 792] = f2bf(fmaxf(fmaf(f3, a, bb), 0.f));
        }
    }

    const int srow = tid >> 2, sc16 = tid & 3;
    f32x4 acc2[4][4];
    #pragma unroll
    for (int i = 0; i < 4; i++)
        #pragma unroll
        for (int j = 0; j < 4; j++) acc2[i][j] = (f32x4){0.f, 0.f, 0.f, 0.f};

    for (int ks = 0; ks < 8; ks++) {
        const int k0 = ks * 32;
        __syncthreads();   // first iter: covers y1s writes
        #pragma unroll
        for (int q = 0; q < 4; q++)
            gload16(Wp2 + (srow + q * 64) * 256 + k0 + sc16 * 8, Bs + q * 2048 + tid * 8);
        __syncthreads();
        bf16x8 af[4], bv[4];
        #pragma unroll
        for (int i = 0; i < 4; i++) af[i] = *(const bf16x8*)(y1s + (i * 16 + tl) * 264 + k0 + quad * 8);
        #pragma unroll
        for (int j = 0; j < 4; j++) bv[j] = *(const bf16x8*)(Bs + (wave * 64 + j * 16 + tl) * 32 + quad * 8);
        #pragma unroll
        for (int i = 0; i < 4; i++)
            #pragma unroll
            for (int j = 0; j < 4; j++)
                acc2[i][j] = __builtin_amdgcn_mfma_f32_16x16x32_bf16(af[i], bv[j], acc2[i][j], 0, 0, 0);
    }

    #pragma unroll
    for (int j = 0; j < 4; j++) {
        int col = wave * 64 + j * 16 + tl;
        float s = 0.f, q2 = 0.f;
        float mx0 = -3.0e38f, mn0 = 3.0e38f, mx1 = -3.0e38f, mn1 = 3.0e38f;
        #pragma unroll
        for (int i = 0; i < 4; i++)
            #pragma unroll
            for (int r = 0; r < 4; r++) {
                float v = acc2[i][j][r];
                s += v; q2 += v * v;
                if (i < 2) { mx0 = fmaxf(mx0, v); mn0 = fminf(mn0, v); }
                else       { mx1 = fmaxf(mx1, v); mn1 = fminf(mn1, v); }
            }
        s += __shfl_xor(s, 16); s += __shfl_xor(s, 32);
        q2 += __shfl_xor(q2, 16); q2 += __shfl_xor(q2, 32);
        mx0 = fmaxf(mx0, __shfl_xor(mx0, 16)); mx0 = fmaxf(mx0, __shfl_xor(mx0, 32));
        mn0 = fminf(mn0, __shfl_xor(mn0, 16)); mn0 = fminf(mn0, __shfl_xor(mn0, 32));
        mx1 = fmaxf(mx1, __shfl_xor(mx1, 16)); mx1 = fmaxf(mx1, __shfl_xor(mx1, 32));
        mn1 = fminf(mn1, __shfl_xor(mn1, 16)); mn1 = fminf(mn1, __shfl_xor(mn1, 32));
        if (quad == 0) {
            psum[(size_t)bx * 256 + col] = s;
            psq[(size_t)bx * 256 + col] = q2;
            size_t p0 = (size_t)(bx * 2) * 256 + col;
            size_t p1 = (size_t)(bx * 2 + 1) * 256 + col;
            ymax[p0] = mx0; ymin[p0] = mn0;
            ymax[p1] = mx1; ymin[p1] = mn1;
        }
    }
}

// ---------------- stats reduction: 64 blocks x 64 rows (coalesced), then 1-block 64-iter finish ------
__global__ __launch_bounds__(256) void reduce1_k(const float* __restrict__ psum, const float* __restrict__ psq,
                                                 float* __restrict__ ps2, float* __restrict__ pq2) {
    int j = blockIdx.x, t = threadIdx.x;
    float s = 0.f, q = 0.f;
    #pragma unroll 4
    for (int kk = 0; kk < 64; kk++) {
        size_t r = (size_t)(j * 64 + kk) * 256 + t;
        s += psum[r]; q += psq[r];
    }
    ps2[j * 256 + t] = s;
    pq2[j * 256 + t] = q;
}

__global__ __launch_bounds__(256) void reduce2_k(const float* __restrict__ ps2, const float* __restrict__ pq2,
                                                 const float* __restrict__ gamma, const float* __restrict__ beta,
                                                 float* __restrict__ ab) {
    int c = threadIdx.x;
    float S = 0.f, Q = 0.f;
    for (int j = 0; j < 64; j++) {
        S += ps2[j * 256 + c];
        Q += pq2[j * 256 + c];
    }
    float mu = S * INV_N;
    float var = Q * INV_N - mu * mu;
    float a = gamma[c] * rsqrtf(var + 1e-5f);
    ab[c] = a;
    ab[256 + c] = beta[c] - mu * a;
}

// ---------------- final: relu(a*(a>=0?max:min)+b), transpose -> (B,O,N) ----------------
__global__ __launch_bounds__(256) void final_k(const float* __restrict__ ymax, const float* __restrict__ ymin,
                                               const float* __restrict__ ab, float* __restrict__ out) {
    __shared__ float sm[32 * 33];
    int b = blockIdx.z;
    int n0 = blockIdx.x * 32, o0 = blockIdx.y * 32;
    int t = threadIdx.x, x = t & 31, y = t >> 5;
    #pragma unroll
    for (int rr = 0; rr < 4; rr++) {
        int n = n0 + y + rr * 8;
        int o = o0 + x;
        float a = ab[o], bb = ab[256 + o];
        size_t p = (size_t)(b * NPTS + n) * 256 + o;
        float v = (a >= 0.f) ? ymax[p] : ymin[p];
        sm[(y + rr * 8) * 33 + x] = fmaxf(fmaf(v, a, bb), 0.f);
    }
    __syncthreads();
    #pragma unroll
    for (int rr = 0; rr < 4; rr++)
        out[((size_t)(b * 256 + o0 + y + rr * 8)) * NPTS + n0 + x] = sm[x * 33 + (y + rr * 8)];
}

extern "C" void kernel_launch(void* const* d_in, const int* in_sizes, int n_in,
                              void* d_out, int out_size, void* d_ws, size_t ws_size,
                              hipStream_t stream) {
    const float* xyz    = (const float*)d_in[0];
    const float* feat   = (const float*)d_in[1];
    const float* rot    = (const float*)d_in[2];
    const float* W1     = (const float*)d_in[3];
    const float* gamma1 = (const float*)d_in[4];
    const float* beta1  = (const float*)d_in[5];
    const float* W2     = (const float*)d_in[6];
    const float* gamma2 = (const float*)d_in[7];
    const float* beta2  = (const float*)d_in[8];
    float* out = (float*)d_out;

    char* ws = (char*)d_ws;
    u16*   featT = (u16*)(ws + 0);           //  4,194,304
    int*   idxp  = (int*)(ws + 4194304);     //  1,048,576
    u16*   gxyz  = (u16*)(ws + 5242880);     //  2,097,152
    u16*   Wp1   = (u16*)(ws + 7340032);     //    147,456
    u16*   Wp2   = (u16*)(ws + 7487488);     //    131,072
    float* ab1   = (float*)(ws + 7618560);   //      2,048
    float* ab2   = (float*)(ws + 7620608);   //      2,048
    float* psum  = (float*)(ws + 7622656);   //  4,194,304
    float* psq   = (float*)(ws + 11816960);  //  4,194,304
    float* ymax  = (float*)(ws + 16011264);  //  8,388,608
    float* ymin  = (float*)(ws + 24399872);  //  8,388,608
    uint2* y1f   = (uint2*)(ws + 32788480);  // 134,217,728 (big path only)
    const size_t BIG_NEED = 32788480ull + 134217728ull;   // 167,006,208

    // stage-2 reduction scratch (64x256 f32 each), borrowed dead regions:
    //  - stats1 reduce runs before pass 2 writes ymin -> borrow ymin region
    //  - stats2 reduce runs after gxyz last use -> borrow gxyz region
    float* r1s = (float*)(ws + 24399872);
    float* r1q = r1s + 16384;
    float* r2s = (float*)(ws + 5242880);
    float* r2q = r2s + 16384;

    query_k<<<2048, 256, 0, stream>>>(xyz, rot, feat, idxp, gxyz, featT, W1, W2, Wp1, Wp2);

    if (ws_size >= BIG_NEED) {
        // pass 1: GEMM1 (BK=64 swizzled phases) + fragment-layout y1 spill + stats1
        fused_k<0, 1><<<NBLK, 256, 0, stream>>>(featT, gxyz, idxp, Wp1, Wp2, ab1, psum, psq, ymax, ymin, y1f);
        reduce1_k<<<64, 256, 0, stream>>>(psum, psq, r1s, r1q);
        reduce2_k<<<1, 256, 0, stream>>>(r1s, r1q, gamma1, beta1, ab1);
        // pass 2: reload y1 frags -> norm/relu -> GEMM2 + stats2 + max/min
        fused2_k<<<NBLK, 256, 0, stream>>>(y1f, Wp2, ab1, psum, psq, ymax, ymin);
        reduce1_k<<<64, 256, 0, stream>>>(psum, psq, r2s, r2q);
        reduce2_k<<<1, 256, 0, stream>>>(r2s, r2q, gamma2, beta2, ab2);
    } else {
        // fallback: recompute GEMM1 in pass 2 (proven path)
        fused_k<0, 0><<<NBLK, 256, 0, stream>>>(featT, gxyz, idxp, Wp1, Wp2, ab1, psum, psq, ymax, ymin, nullptr);
        reduce1_k<<<64, 256, 0, stream>>>(psum, psq, r1s, r1q);
        reduce2_k<<<1, 256, 0, stream>>>(r1s, r1q, gamma1, beta1, ab1);
        fused_k<1, 0><<<NBLK, 256, 0, stream>>>(featT, gxyz, idxp, Wp1, Wp2, ab1, psum, psq, ymax, ymin, nullptr);
        reduce1_k<<<64, 256, 0, stream>>>(psum, psq, r2s, r2q);
        reduce2_k<<<1, 256, 0, stream>>>(r2s, r2q, gamma2, beta2, ab2);
    }
    final_k<<<dim3(64, 8, 4), 256, 0, stream>>>(ymax, ymin, ab2, out);
}

// Round 11
// 231.247 us; speedup vs baseline: 1.9794x; 1.0034x over previous
//
#include <hip/hip_runtime.h>

typedef unsigned short u16;
typedef unsigned int u32;
typedef __attribute__((ext_vector_type(8))) short bf16x8;
typedef __attribute__((ext_vector_type(4))) float f32x4;

#define NPTS 2048
#define CFEAT 256
#define NS 32
#define MTOT 262144           // 4*2048*32
#define NBLK 4096             // MTOT/64 m-tiles
#define INV_N (1.0f/262144.0f)

__device__ __forceinline__ float bf2f(u16 u) {
    union { u32 i; float f; } v; v.i = ((u32)u) << 16; return v.f;
}
__device__ __forceinline__ u16 f2bf(float f) {
    union { float f; u32 i; } v; v.f = f;
    u32 i = v.i;
    return (u16)((i + 0x7fffu + ((i >> 16) & 1u)) >> 16);
}

// async global->LDS, 16B per lane. LDS dest = wave-uniform base + lane*16; global src per-lane.
__device__ __forceinline__ void gload16(const void* g, void* l) {
    __builtin_amdgcn_global_load_lds((const __attribute__((address_space(1))) void*)g,
                                     (__attribute__((address_space(3))) void*)l, 16, 0, 0);
}

// ---------------- cylinder query + gxyz + folded W-prep (blocks 0..255) + folded featT tile ----------
__global__ __launch_bounds__(256) void query_k(const float* __restrict__ xyz, const float* __restrict__ rot,
                                               const float* __restrict__ feat,
                                               int* __restrict__ idx, u16* __restrict__ gxyz,
                                               u16* __restrict__ featT,
                                               const float* __restrict__ W1, const float* __restrict__ W2,
                                               u16* __restrict__ Wp1, u16* __restrict__ Wp2) {
    __shared__ float sm[32 * 33];
    __shared__ int sidx[4 * NS];
    const int tid = threadIdx.x;
    // folded prep: pack W1 -> [feat(256)|xyz(3)|0(29)] (K=288), W2 (K=256), bf16
    if (blockIdx.x < 256) {
        int o = blockIdx.x;
        Wp1[o * 288 + tid] = f2bf(W1[o * 259 + 3 + tid]);
        if (tid < 32) Wp1[o * 288 + 256 + tid] = (tid < 3) ? f2bf(W1[o * 259 + tid]) : (u16)0;
        Wp2[o * 256 + tid] = f2bf(W2[o * 256 + tid]);
    }
    // folded featT tile: (B,C,N) fp32 -> (B,N,C) bf16, old grid (64,8,4) linearized
    {
        int bb = blockIdx.x >> 9;
        int c0 = ((blockIdx.x >> 6) & 7) * 32;
        int n0 = (blockIdx.x & 63) * 32;
        int x = tid & 31, y = tid >> 5;
        #pragma unroll
        for (int rr = 0; rr < 4; rr++) {
            int c = c0 + y + rr * 8;
            sm[(y + rr * 8) * 33 + x] = feat[((size_t)(bb * CFEAT + c)) * NPTS + n0 + x];
        }
        __syncthreads();
        #pragma unroll
        for (int rr = 0; rr < 4; rr++) {
            int n = n0 + y + rr * 8;
            featT[((size_t)(bb * NPTS + n)) * CFEAT + c0 + x] = f2bf(sm[x * 33 + (y + rr * 8)]);
        }
    }
    // cylinder query (wave per point) + gxyz emit
    const int wid = tid >> 6;
    const int pid = blockIdx.x * 4 + wid;
    const int lane = tid & 63;
    const int b = pid >> 11, p = pid & 2047;
    const float* xb = xyz + (size_t)b * NPTS * 3;
    float px = xb[p * 3 + 0], py = xb[p * 3 + 1], pz = xb[p * 3 + 2];
    const float* rp = rot + (size_t)pid * 9;
    float r00 = rp[0], r01 = rp[1], r02 = rp[2];
    float r10 = rp[3], r11 = rp[4], r12 = rp[5];
    float r20 = rp[6], r21 = rp[7], r22 = rp[8];
    int cnt = 0, first = 0;
    for (int n0 = 0; n0 < NPTS && cnt < NS; n0 += 64) {
        int n = n0 + lane;
        // exact fp32, sequential order, no fma contraction -> match numpy mask bitwise
        float dx = __fsub_rn(xb[n * 3 + 0], px);
        float dy = __fsub_rn(xb[n * 3 + 1], py);
        float dz = __fsub_rn(xb[n * 3 + 2], pz);
        float a0 = __fadd_rn(__fadd_rn(__fmul_rn(r00, dx), __fmul_rn(r01, dy)), __fmul_rn(r02, dz));
        float a1 = __fadd_rn(__fadd_rn(__fmul_rn(r10, dx), __fmul_rn(r11, dy)), __fmul_rn(r12, dz));
        float a2 = __fadd_rn(__fadd_rn(__fmul_rn(r20, dx), __fmul_rn(r21, dy)), __fmul_rn(r22, dz));
        float t2 = __fadd_rn(__fmul_rn(a1, a1), __fmul_rn(a2, a2));
        bool valid = (t2 < 0.0025f) && (a0 > -0.02f) && (a0 < 0.04f);
        unsigned long long bal = __ballot(valid);
        if (cnt == 0 && bal) first = n0 + __builtin_ctzll(bal);
        int rank = __builtin_popcountll(bal & ((1ull << lane) - 1ull));
        int slot = cnt + rank;
        if (valid && slot < NS) sidx[wid * NS + slot] = n;
        cnt += __builtin_popcountll(bal);
    }
    int filled = cnt < NS ? cnt : NS;
    __syncthreads();   // sidx visible
    if (lane < NS) {
        int i = (lane < filled) ? sidx[wid * NS + lane] : (cnt > 0 ? first : 0);
        idx[(size_t)pid * NS + lane] = i;
        float dx = (xb[i * 3 + 0] - px) * 20.0f;
        float dy = (xb[i * 3 + 1] - py) * 20.0f;
        float dz = (xb[i * 3 + 2] - pz) * 20.0f;
        float g0 = dx * r00 + dy * r10 + dz * r20;
        float g1 = dx * r01 + dy * r11 + dz * r21;
        float g2 = dx * r02 + dy * r12 + dz * r22;
        uint2 v;
        v.x = (u32)f2bf(g0) | ((u32)f2bf(g1) << 16);
        v.y = (u32)f2bf(g2);
        *(uint2*)(gxyz + ((size_t)pid * NS + lane) * 4) = v;
    }
}

// ---------------- fused GEMM1 (+optional norm1+GEMM2) over one 64-row m-tile ----------------
// GEMM1 BK=64: 4 feat phases + 1 xyz phase. Stride-64 LDS rows pre-swizzle the GLOBAL source slot
// (linear LDS dest) and MFMA reads XOR the same pattern: slot' = slot ^ (row&7).
// Column ownership REMAPPED (round-6-proven): col = j*64 + wave*16 + tl, so each wave owns
// j-tiles 0,1 in channels 0..127 (enables K-halved y1s in pass 2). Bitwise-identical per-col math.
// FULL=0: stats1 partials (+y1 fragment spill when STORE=1).
// FULL=1: recompute GEMM1, norm1+relu -> LDS -> GEMM2 (fallback path, BK=32 GEMM2).
template <int FULL, int STORE>
__global__ __launch_bounds__(256) void fused_k(
    const u16* __restrict__ featT, const u16* __restrict__ gxyz, const int* __restrict__ idx,
    const u16* __restrict__ Wp1, const u16* __restrict__ Wp2, const float* __restrict__ ab1,
    float* __restrict__ psum, float* __restrict__ psq,
    float* __restrict__ ymax, float* __restrict__ ymin, uint2* __restrict__ y1f)
{
    __shared__ __attribute__((aligned(16))) u16 As[64 * 64];     //  8 KB
    __shared__ __attribute__((aligned(16))) u16 Bs[256 * 64];    // 32 KB
    __shared__ __attribute__((aligned(16))) u16 y1s[FULL ? 64 * 264 : 16];
    __shared__ int rowbase_s[64];

    const int tid = threadIdx.x;
    const int lane = tid & 63, wave = tid >> 6;
    const int quad = lane >> 4, tl = lane & 15;
    const int bx = blockIdx.x;
    const int m0 = bx * 64;

    if (tid < 64) {
        int m = m0 + tid;
        int gi = idx[m];
        int b = m >> 16;
        rowbase_s[tid] = (b * NPTS + gi) * CFEAT;
    }
    __syncthreads();

    // staging geometry: thread covers (row = tid>>3 [+32], dest slot = tid&7); source slot
    // pre-swizzled so LDS holds slot s at position s^(row&7).
    const int sr8 = tid >> 3;                 // 0..31
    const int koffA = (((tid & 7) ^ (sr8 & 7)) * 8);

    f32x4 acc[4][4];
    #pragma unroll
    for (int i = 0; i < 4; i++)
        #pragma unroll
        for (int j = 0; j < 4; j++) acc[i][j] = (f32x4){0.f, 0.f, 0.f, 0.f};

    // ---- GEMM1: 4 feat phases (BK=64) ----
    for (int t = 0; t < 4; t++) {
        const int k0 = t * 64;
        __syncthreads();
        gload16(featT + rowbase_s[sr8] + k0 + koffA, As + tid * 8);
        gload16(featT + rowbase_s[sr8 + 32] + k0 + koffA, As + 2048 + tid * 8);
        #pragma unroll
        for (int c = 0; c < 8; c++)
            gload16(Wp1 + (c * 32 + sr8) * 288 + k0 + koffA, Bs + c * 2048 + tid * 8);
        __syncthreads();   // vmcnt(0) drain: tiles landed
        #pragma unroll
        for (int kk = 0; kk < 2; kk++) {
            bf16x8 af[4], bv[4];
            #pragma unroll
            for (int i = 0; i < 4; i++)
                af[i] = *(const bf16x8*)(As + (i * 16 + tl) * 64 + (((kk * 4 + quad) ^ (tl & 7)) * 8));
            #pragma unroll
            for (int j = 0; j < 4; j++)
                bv[j] = *(const bf16x8*)(Bs + (j * 64 + wave * 16 + tl) * 64 + (((kk * 4 + quad) ^ (tl & 7)) * 8));
            #pragma unroll
            for (int i = 0; i < 4; i++)
                #pragma unroll
                for (int j = 0; j < 4; j++)
                    acc[i][j] = __builtin_amdgcn_mfma_f32_16x16x32_bf16(af[i], bv[j], acc[i][j], 0, 0, 0);
        }
    }
    // ---- xyz phase (K=32, register-staged with swizzled ds_write) ----
    {
        __syncthreads();
        const int srow = tid >> 2, sc16 = tid & 3;
        uint4 va = make_uint4(0, 0, 0, 0);
        if (sc16 == 0) {
            uint2 g2 = *(const uint2*)(gxyz + (size_t)(m0 + srow) * 4);
            va.x = g2.x; va.y = g2.y;
        }
        *(uint4*)(As + srow * 64 + ((sc16 ^ (srow & 7)) * 8)) = va;
        #pragma unroll
        for (int s = 0; s < 4; s++) {
            uint4 w = *(const uint4*)(Wp1 + tid * 288 + 256 + s * 8);
            *(uint4*)(Bs + tid * 64 + ((s ^ (tid & 7)) * 8)) = w;
        }
        __syncthreads();
        bf16x8 af[4], bv[4];
        #pragma unroll
        for (int i = 0; i < 4; i++)
            af[i] = *(const bf16x8*)(As + (i * 16 + tl) * 64 + ((quad ^ (tl & 7)) * 8));
        #pragma unroll
        for (int j = 0; j < 4; j++)
            bv[j] = *(const bf16x8*)(Bs + (j * 64 + wave * 16 + tl) * 64 + ((quad ^ (tl & 7)) * 8));
        #pragma unroll
        for (int i = 0; i < 4; i++)
            #pragma unroll
            for (int j = 0; j < 4; j++)
                acc[i][j] = __builtin_amdgcn_mfma_f32_16x16x32_bf16(af[i], bv[j], acc[i][j], 0, 0, 0);
    }

    if (!FULL) {
        #pragma unroll
        for (int j = 0; j < 4; j++) {
            float s = 0.f, q2 = 0.f;
            #pragma unroll
            for (int i = 0; i < 4; i++) {
                float v0 = acc[i][j][0], v1 = acc[i][j][1], v2 = acc[i][j][2], v3 = acc[i][j][3];
                if (STORE) {
                    u32 lo = (u32)f2bf(v0) | ((u32)f2bf(v1) << 16);
                    u32 hi = (u32)f2bf(v2) | ((u32)f2bf(v3) << 16);
                    y1f[((size_t)(bx * 4 + wave) * 16 + i * 4 + j) * 64 + lane] = make_uint2(lo, hi);
                    // stats on the rounded values for self-consistency with pass 2
                    v0 = bf2f((u16)(lo & 0xffff)); v1 = bf2f((u16)(lo >> 16));
                    v2 = bf2f((u16)(hi & 0xffff)); v3 = bf2f((u16)(hi >> 16));
                }
                s += v0 + v1 + v2 + v3;
                q2 += v0 * v0 + v1 * v1 + v2 * v2 + v3 * v3;
            }
            s += __shfl_xor(s, 16); s += __shfl_xor(s, 32);
            q2 += __shfl_xor(q2, 16); q2 += __shfl_xor(q2, 32);
            if (quad == 0) {
                int col = j * 64 + wave * 16 + tl;
                psum[(size_t)bx * 256 + col] = s;
                psq[(size_t)bx * 256 + col] = q2;
            }
        }
        return;
    }

    // ---- norm1 + relu -> y1s (bf16), remapped cols ----
    #pragma unroll
    for (int j = 0; j < 4; j++) {
        int col = j * 64 + wave * 16 + tl;
        float a = ab1[col], bb = ab1[256 + col];
        #pragma unroll
        for (int i = 0; i < 4; i++)
            #pragma unroll
            for (int r = 0; r < 4; r++) {
                float v = fmaxf(fmaf(acc[i][j][r], a, bb), 0.f);
                y1s[(i * 16 + quad * 4 + r) * 264 + col] = f2bf(v);
            }
    }

    // ---- GEMM2 (BK=32; uses first 16KB of Bs with stride-32 mapping) ----
    const int srow = tid >> 2, sc16 = tid & 3;
    f32x4 acc2[4][4];
    #pragma unroll
    for (int i = 0; i < 4; i++)
        #pragma unroll
        for (int j = 0; j < 4; j++) acc2[i][j] = (f32x4){0.f, 0.f, 0.f, 0.f};
    for (int ks = 0; ks < 8; ks++) {
        const int k0 = ks * 32;
        __syncthreads();
        #pragma unroll
        for (int q = 0; q < 4; q++)
            gload16(Wp2 + (srow + q * 64) * 256 + k0 + sc16 * 8, Bs + q * 2048 + tid * 8);
        __syncthreads();
        bf16x8 af[4], bv[4];
        #pragma unroll
        for (int i = 0; i < 4; i++) af[i] = *(const bf16x8*)(y1s + (i * 16 + tl) * 264 + k0 + quad * 8);
        #pragma unroll
        for (int j = 0; j < 4; j++) bv[j] = *(const bf16x8*)(Bs + (j * 64 + wave * 16 + tl) * 32 + quad * 8);
        #pragma unroll
        for (int i = 0; i < 4; i++)
            #pragma unroll
            for (int j = 0; j < 4; j++)
                acc2[i][j] = __builtin_amdgcn_mfma_f32_16x16x32_bf16(af[i], bv[j], acc2[i][j], 0, 0, 0);
    }

    // ---- epilogue2 ----
    #pragma unroll
    for (int j = 0; j < 4; j++) {
        int col = j * 64 + wave * 16 + tl;
        float s = 0.f, q2 = 0.f;
        float mx0 = -3.0e38f, mn0 = 3.0e38f, mx1 = -3.0e38f, mn1 = 3.0e38f;
        #pragma unroll
        for (int i = 0; i < 4; i++)
            #pragma unroll
            for (int r = 0; r < 4; r++) {
                float v = acc2[i][j][r];
                s += v; q2 += v * v;
                if (i < 2) { mx0 = fmaxf(mx0, v); mn0 = fminf(mn0, v); }
                else       { mx1 = fmaxf(mx1, v); mn1 = fminf(mn1, v); }
            }
        s += __shfl_xor(s, 16); s += __shfl_xor(s, 32);
        q2 += __shfl_xor(q2, 16); q2 += __shfl_xor(q2, 32);
        mx0 = fmaxf(mx0, __shfl_xor(mx0, 16)); mx0 = fmaxf(mx0, __shfl_xor(mx0, 32));
        mn0 = fminf(mn0, __shfl_xor(mn0, 16)); mn0 = fminf(mn0, __shfl_xor(mn0, 32));
        mx1 = fmaxf(mx1, __shfl_xor(mx1, 16)); mx1 = fmaxf(mx1, __shfl_xor(mx1, 32));
        mn1 = fminf(mn1, __shfl_xor(mn1, 16)); mn1 = fminf(mn1, __shfl_xor(mn1, 32));
        if (quad == 0) {
            psum[(size_t)bx * 256 + col] = s;
            psq[(size_t)bx * 256 + col] = q2;
            size_t p0 = (size_t)(bx * 2) * 256 + col;
            size_t p1 = (size_t)(bx * 2 + 1) * 256 + col;
            ymax[p0] = mx0; ymin[p0] = mn0;
            ymax[p1] = mx1; ymin[p1] = mn1;
        }
    }
}

// ---------------- pass 2 (big-ws path): reload y1 frags, norm+relu -> K-halved LDS -> BK=64 GEMM2 ----
// y1s = 64x136 half-buffer (channels 0..127, then 128..255 deposited after phase 1's reads drain).
// Bs = 256x64 staged with the source-slot swizzle. 4 phases (was 8). LDS total 50176 B (unchanged).
__global__ __launch_bounds__(256) void fused2_k(
    const uint2* __restrict__ y1f, const u16* __restrict__ Wp2, const float* __restrict__ ab1,
    float* __restrict__ psum, float* __restrict__ psq,
    float* __restrict__ ymax, float* __restrict__ ymin)
{
    __shared__ __attribute__((aligned(16))) u16 Bs[256 * 64];    // 32 KB
    __shared__ __attribute__((aligned(16))) u16 y1s[64 * 136];   // 17 KB (half of y1)
    const int tid = threadIdx.x;
    const int lane = tid & 63, wave = tid >> 6;
    const int quad = lane >> 4, tl = lane & 15;
    const int bx = blockIdx.x;
    const int sr8 = tid >> 3;
    const int koffB = (((tid & 7) ^ (sr8 & 7)) * 8);

    // reload pass-1 fragments once (coalesced), keep normalized values in registers
    float yv[4][4][4];   // [j][i][r]
    #pragma unroll
    for (int j = 0; j < 4; j++) {
        int col = j * 64 + wave * 16 + tl;
        float a = ab1[col], bb = ab1[256 + col];
        #pragma unroll
        for (int i = 0; i < 4; i++) {
            uint2 v = y1f[((size_t)(bx * 4 + wave) * 16 + i * 4 + j) * 64 + lane];
            yv[j][i][0] = fmaxf(fmaf(bf2f((u16)(v.x & 0xffff)), a, bb), 0.f);
            yv[j][i][1] = fmaxf(fmaf(bf2f((u16)(v.x >> 16)), a, bb), 0.f);
            yv[j][i][2] = fmaxf(fmaf(bf2f((u16)(v.y & 0xffff)), a, bb), 0.f);
            yv[j][i][3] = fmaxf(fmaf(bf2f((u16)(v.y >> 16)), a, bb), 0.f);
        }
    }
    // deposit K-half 0 (channels 0..127 = j=0,1 of every wave)
    #pragma unroll
    for (int j = 0; j < 2; j++) {
        int col = j * 64 + wave * 16 + tl;
        #pragma unroll
        for (int i = 0; i < 4; i++)
            #pragma unroll
            for (int r = 0; r < 4; r++)
                y1s[(i * 16 + quad * 4 + r) * 136 + col] = f2bf(yv[j][i][r]);
    }

    f32x4 acc2[4][4];
    #pragma unroll
    for (int i = 0; i < 4; i++)
        #pragma unroll
        for (int j = 0; j < 4; j++) acc2[i][j] = (f32x4){0.f, 0.f, 0.f, 0.f};

    for (int t = 0; t < 4; t++) {
        const int k0 = t * 64;
        __syncthreads();   // prev phase's reads done (first iter: y1s half-0 writes visible soon)
        if (t == 2) {      // phase-1 reads of half-0 complete -> deposit half-1 (channels 128..255)
            #pragma unroll
            for (int j = 2; j < 4; j++) {
                int lc = (j - 2) * 64 + wave * 16 + tl;
                #pragma unroll
                for (int i = 0; i < 4; i++)
                    #pragma unroll
                    for (int r = 0; r < 4; r++)
                        y1s[(i * 16 + quad * 4 + r) * 136 + lc] = f2bf(yv[j][i][r]);
            }
        }
        #pragma unroll
        for (int c = 0; c < 8; c++)
            gload16(Wp2 + (c * 32 + sr8) * 256 + k0 + koffB, Bs + c * 2048 + tid * 8);
        __syncthreads();   // drains gload16 (vmcnt) + ds_writes (lgkm)
        const int klb = (t & 1) * 64;    // k-base within the half-buffer
        #pragma unroll
        for (int kk = 0; kk < 2; kk++) {
            bf16x8 af[4], bv[4];
            #pragma unroll
            for (int i = 0; i < 4; i++)
                af[i] = *(const bf16x8*)(y1s + (i * 16 + tl) * 136 + klb + kk * 32 + quad * 8);
            #pragma unroll
            for (int j = 0; j < 4; j++)
                bv[j] = *(const bf16x8*)(Bs + (j * 64 + wave * 16 + tl) * 64 + (((kk * 4 + quad) ^ (tl & 7)) * 8));
            #pragma unroll
            for (int i = 0; i < 4; i++)
                #pragma unroll
                for (int j = 0; j < 4; j++)
                    acc2[i][j] = __builtin_amdgcn_mfma_f32_16x16x32_bf16(af[i], bv[j], acc2[i][j], 0, 0, 0);
        }
    }

    #pragma unroll
    for (int j = 0; j < 4; j++) {
        int col = j * 64 + wave * 16 + tl;
        float s = 0.f, q2 = 0.f;
        float mx0 = -3.0e38f, mn0 = 3.0e38f, mx1 = -3.0e38f, mn1 = 3.0e38f;
        #pragma unroll
        for (int i = 0; i < 4; i++)
            #pragma unroll
            for (int r = 0; r < 4; r++) {
                float v = acc2[i][j][r];
                s += v; q2 += v * v;
                if (i < 2) { mx0 = fmaxf(mx0, v); mn0 = fminf(mn0, v); }
                else       { mx1 = fmaxf(mx1, v); mn1 = fminf(mn1, v); }
            }
        s += __shfl_xor(s, 16); s += __shfl_xor(s, 32);
        q2 += __shfl_xor(q2, 16); q2 += __shfl_xor(q2, 32);
        mx0 = fmaxf(mx0, __shfl_xor(mx0, 16)); mx0 = fmaxf(mx0, __shfl_xor(mx0, 32));
        mn0 = fminf(mn0, __shfl_xor(mn0, 16)); mn0 = fminf(mn0, __shfl_xor(mn0, 32));
        mx1 = fmaxf(mx1, __shfl_xor(mx1, 16)); mx1 = fmaxf(mx1, __shfl_xor(mx1, 32));
        mn1 = fminf(mn1, __shfl_xor(mn1, 16)); mn1 = fminf(mn1, __shfl_xor(mn1, 32));
        if (quad == 0) {
            psum[(size_t)bx * 256 + col] = s;
            psq[(size_t)bx * 256 + col] = q2;
            size_t p0 = (size_t)(bx * 2) * 256 + col;
            size_t p1 = (size_t)(bx * 2 + 1) * 256 + col;
            ymax[p0] = mx0; ymin[p0] = mn0;
            ymax[p1] = mx1; ymin[p1] = mn1;
        }
    }
}

// ---------------- stats reduction: 64 blocks x 64 rows (coalesced), then 1-block 64-iter finish ------
__global__ __launch_bounds__(256) void reduce1_k(const float* __restrict__ psum, const float* __restrict__ psq,
                                                 float* __restrict__ ps2, float* __restrict__ pq2) {
    int j = blockIdx.x, t = threadIdx.x;
    float s = 0.f, q = 0.f;
    #pragma unroll 4
    for (int kk = 0; kk < 64; kk++) {
        size_t r = (size_t)(j * 64 + kk) * 256 + t;
        s += psum[r]; q += psq[r];
    }
    ps2[j * 256 + t] = s;
    pq2[j * 256 + t] = q;
}

__global__ __launch_bounds__(256) void reduce2_k(const float* __restrict__ ps2, const float* __restrict__ pq2,
                                                 const float* __restrict__ gamma, const float* __restrict__ beta,
                                                 float* __restrict__ ab) {
    int c = threadIdx.x;
    float S = 0.f, Q = 0.f;
    for (int j = 0; j < 64; j++) {
        S += ps2[j * 256 + c];
        Q += pq2[j * 256 + c];
    }
    float mu = S * INV_N;
    float var = Q * INV_N - mu * mu;
    float a = gamma[c] * rsqrtf(var + 1e-5f);
    ab[c] = a;
    ab[256 + c] = beta[c] - mu * a;
}

// ---------------- final: relu(a*(a>=0?max:min)+b), transpose -> (B,O,N) ----------------
__global__ __launch_bounds__(256) void final_k(const float* __restrict__ ymax, const float* __restrict__ ymin,
                                               const float* __restrict__ ab, float* __restrict__ out) {
    __shared__ float sm[32 * 33];
    int b = blockIdx.z;
    int n0 = blockIdx.x * 32, o0 = blockIdx.y * 32;
    int t = threadIdx.x, x = t & 31, y = t >> 5;
    #pragma unroll
    for (int rr = 0; rr < 4; rr++) {
        int n = n0 + y + rr * 8;
        int o = o0 + x;
        float a = ab[o], bb = ab[256 + o];
        size_t p = (size_t)(b * NPTS + n) * 256 + o;
        float v = (a >= 0.f) ? ymax[p] : ymin[p];
        sm[(y + rr * 8) * 33 + x] = fmaxf(fmaf(v, a, bb), 0.f);
    }
    __syncthreads();
    #pragma unroll
    for (int rr = 0; rr < 4; rr++)
        out[((size_t)(b * 256 + o0 + y + rr * 8)) * NPTS + n0 + x] = sm[x * 33 + (y + rr * 8)];
}

extern "C" void kernel_launch(void* const* d_in, const int* in_sizes, int n_in,
                              void* d_out, int out_size, void* d_ws, size_t ws_size,
                              hipStream_t stream) {
    const float* xyz    = (const float*)d_in[0];
    const float* feat   = (const float*)d_in[1];
    const float* rot    = (const float*)d_in[2];
    const float* W1     = (const float*)d_in[3];
    const float* gamma1 = (const float*)d_in[4];
    const float* beta1  = (const float*)d_in[5];
    const float* W2     = (const float*)d_in[6];
    const float* gamma2 = (const float*)d_in[7];
    const float* beta2  = (const float*)d_in[8];
    float* out = (float*)d_out;

    char* ws = (char*)d_ws;
    u16*   featT = (u16*)(ws + 0);           //  4,194,304
    int*   idxp  = (int*)(ws + 4194304);     //  1,048,576
    u16*   gxyz  = (u16*)(ws + 5242880);     //  2,097,152
    u16*   Wp1   = (u16*)(ws + 7340032);     //    147,456
    u16*   Wp2   = (u16*)(ws + 7487488);     //    131,072
    float* ab1   = (float*)(ws + 7618560);   //      2,048
    float* ab2   = (float*)(ws + 7620608);   //      2,048
    float* psum  = (float*)(ws + 7622656);   //  4,194,304
    float* psq   = (float*)(ws + 11816960);  //  4,194,304
    float* ymax  = (float*)(ws + 16011264);  //  8,388,608
    float* ymin  = (float*)(ws + 24399872);  //  8,388,608
    uint2* y1f   = (uint2*)(ws + 32788480);  // 134,217,728 (big path only)
    const size_t BIG_NEED = 32788480ull + 134217728ull;   // 167,006,208

    // stage-2 reduction scratch (64x256 f32 each), borrowed dead regions:
    //  - stats1 reduce runs before pass 2 writes ymin -> borrow ymin region
    //  - stats2 reduce runs after gxyz last use -> borrow gxyz region
    float* r1s = (float*)(ws + 24399872);
    float* r1q = r1s + 16384;
    float* r2s = (float*)(ws + 5242880);
    float* r2q = r2s + 16384;

    query_k<<<2048, 256, 0, stream>>>(xyz, rot, feat, idxp, gxyz, featT, W1, W2, Wp1, Wp2);

    if (ws_size >= BIG_NEED) {
        // pass 1: GEMM1 (BK=64 swizzled phases) + fragment-layout y1 spill + stats1
        fused_k<0, 1><<<NBLK, 256, 0, stream>>>(featT, gxyz, idxp, Wp1, Wp2, ab1, psum, psq, ymax, ymin, y1f);
        reduce1_k<<<64, 256, 0, stream>>>(psum, psq, r1s, r1q);
        reduce2_k<<<1, 256, 0, stream>>>(r1s, r1q, gamma1, beta1, ab1);
        // pass 2: reload y1 frags -> norm/relu -> BK=64 GEMM2 (K-halved y1s) + stats2 + max/min
        fused2_k<<<NBLK, 256, 0, stream>>>(y1f, Wp2, ab1, psum, psq, ymax, ymin);
        reduce1_k<<<64, 256, 0, stream>>>(psum, psq, r2s, r2q);
        reduce2_k<<<1, 256, 0, stream>>>(r2s, r2q, gamma2, beta2, ab2);
    } else {
        // fallback: recompute GEMM1 in pass 2 (proven path)
        fused_k<0, 0><<<NBLK, 256, 0, stream>>>(featT, gxyz, idxp, Wp1, Wp2, ab1, psum, psq, ymax, ymin, nullptr);
        reduce1_k<<<64, 256, 0, stream>>>(psum, psq, r1s, r1q);
        reduce2_k<<<1, 256, 0, stream>>>(r1s, r1q, gamma1, beta1, ab1);
        fused_k<1, 0><<<NBLK, 256, 0, stream>>>(featT, gxyz, idxp, Wp1, Wp2, ab1, psum, psq, ymax, ymin, nullptr);
        reduce1_k<<<64, 256, 0, stream>>>(psum, psq, r2s, r2q);
        reduce2_k<<<1, 256, 0, stream>>>(r2s, r2q, gamma2, beta2, ab2);
    }
    final_k<<<dim3(64, 8, 4), 256, 0, stream>>>(ymax, ymin, ab2, out);
}

// Round 12
// 227.221 us; speedup vs baseline: 2.0145x; 1.0177x over previous
//
#include <hip/hip_runtime.h>

typedef unsigned short u16;
typedef unsigned int u32;
typedef __attribute__((ext_vector_type(8))) short bf16x8;
typedef __attribute__((ext_vector_type(4))) float f32x4;

#define NPTS 2048
#define CFEAT 256
#define NS 32
#define MTOT 262144           // 4*2048*32
#define NBLK 4096             // MTOT/64 m-tiles
#define INV_N (1.0f/262144.0f)

__device__ __forceinline__ float bf2f(u16 u) {
    union { u32 i; float f; } v; v.i = ((u32)u) << 16; return v.f;
}
__device__ __forceinline__ u16 f2bf(float f) {
    union { float f; u32 i; } v; v.f = f;
    u32 i = v.i;
    return (u16)((i + 0x7fffu + ((i >> 16) & 1u)) >> 16);
}
// HW packed f32->bf16 (RNE, matches f2bf on finite values): lo16=bf(a), hi16=bf(b). 1 instr vs ~8.
__device__ __forceinline__ u32 pk2bf(float a, float b) {
    u32 r;
    asm("v_cvt_pk_bf16_f32 %0, %1, %2" : "=v"(r) : "v"(a), "v"(b));
    return r;
}

// async global->LDS, 16B per lane. LDS dest = wave-uniform base + lane*16; global src per-lane.
__device__ __forceinline__ void gload16(const void* g, void* l) {
    __builtin_amdgcn_global_load_lds((const __attribute__((address_space(1))) void*)g,
                                     (__attribute__((address_space(3))) void*)l, 16, 0, 0);
}

// ---------------- cylinder query + gxyz + folded W-prep (blocks 0..255) + folded featT tile ----------
// xyz for the block's batch is staged into LDS once (24 KB); the ballot scan then runs on LDS
// (~120cy reads vs ~200-900cy global), exact fp32 values -> mask bitwise unchanged.
__global__ __launch_bounds__(256) void query_k(const float* __restrict__ xyz, const float* __restrict__ rot,
                                               const float* __restrict__ feat,
                                               int* __restrict__ idx, u16* __restrict__ gxyz,
                                               u16* __restrict__ featT,
                                               const float* __restrict__ W1, const float* __restrict__ W2,
                                               u16* __restrict__ Wp1, u16* __restrict__ Wp2) {
    __shared__ float sm[32 * 33];        //  4.2 KB (featT transpose tile)
    __shared__ float xbs[NPTS * 3];      // 24.6 KB (batch xyz)
    __shared__ int sidx[4 * NS];
    const int tid = threadIdx.x;
    // folded prep: pack W1 -> [feat(256)|xyz(3)|0(29)] (K=288), W2 (K=256), bf16
    if (blockIdx.x < 256) {
        int o = blockIdx.x;
        Wp1[o * 288 + tid] = f2bf(W1[o * 259 + 3 + tid]);
        if (tid < 32) Wp1[o * 288 + 256 + tid] = (tid < 3) ? f2bf(W1[o * 259 + tid]) : (u16)0;
        Wp2[o * 256 + tid] = f2bf(W2[o * 256 + tid]);
    }
    const int b = blockIdx.x >> 9;       // batch (same for featT fold and scan: (bx*4+wid)>>11 == bx>>9)
    const float* xb = xyz + (size_t)b * NPTS * 3;
    // featT fold part 1: feat tile -> sm
    const int c0 = ((blockIdx.x >> 6) & 7) * 32;
    const int n0f = (blockIdx.x & 63) * 32;
    {
        int x = tid & 31, y = tid >> 5;
        #pragma unroll
        for (int rr = 0; rr < 4; rr++) {
            int c = c0 + y + rr * 8;
            sm[(y + rr * 8) * 33 + x] = feat[((size_t)(b * CFEAT + c)) * NPTS + n0f + x];
        }
    }
    // stage batch xyz -> LDS (6144 floats = 1536 uint4, 6 per thread, coalesced)
    {
        const uint4* src = (const uint4*)xb;
        uint4* dst = (uint4*)xbs;
        #pragma unroll
        for (int u = 0; u < 6; u++) dst[u * 256 + tid] = src[u * 256 + tid];
    }
    __syncthreads();                     // covers sm + xbs
    // featT fold part 2: transpose out (bf16 via HW cvt)
    {
        int x = tid & 31, y = tid >> 5;
        #pragma unroll
        for (int rr = 0; rr < 4; rr++) {
            int n = n0f + y + rr * 8;
            featT[((size_t)(b * NPTS + n)) * CFEAT + c0 + x] = (u16)pk2bf(sm[x * 33 + (y + rr * 8)], 0.f);
        }
    }
    // cylinder query (wave per point) on LDS xyz + gxyz emit
    const int wid = tid >> 6;
    const int pid = blockIdx.x * 4 + wid;
    const int lane = tid & 63;
    const int p = pid & 2047;
    float px = xbs[p * 3 + 0], py = xbs[p * 3 + 1], pz = xbs[p * 3 + 2];
    const float* rp = rot + (size_t)pid * 9;
    float r00 = rp[0], r01 = rp[1], r02 = rp[2];
    float r10 = rp[3], r11 = rp[4], r12 = rp[5];
    float r20 = rp[6], r21 = rp[7], r22 = rp[8];
    int cnt = 0, first = 0;
    for (int n0 = 0; n0 < NPTS && cnt < NS; n0 += 64) {
        int n = n0 + lane;
        // exact fp32, sequential order, no fma contraction -> match numpy mask bitwise
        float dx = __fsub_rn(xbs[n * 3 + 0], px);
        float dy = __fsub_rn(xbs[n * 3 + 1], py);
        float dz = __fsub_rn(xbs[n * 3 + 2], pz);
        float a0 = __fadd_rn(__fadd_rn(__fmul_rn(r00, dx), __fmul_rn(r01, dy)), __fmul_rn(r02, dz));
        float a1 = __fadd_rn(__fadd_rn(__fmul_rn(r10, dx), __fmul_rn(r11, dy)), __fmul_rn(r12, dz));
        float a2 = __fadd_rn(__fadd_rn(__fmul_rn(r20, dx), __fmul_rn(r21, dy)), __fmul_rn(r22, dz));
        float t2 = __fadd_rn(__fmul_rn(a1, a1), __fmul_rn(a2, a2));
        bool valid = (t2 < 0.0025f) && (a0 > -0.02f) && (a0 < 0.04f);
        unsigned long long bal = __ballot(valid);
        if (cnt == 0 && bal) first = n0 + __builtin_ctzll(bal);
        int rank = __builtin_popcountll(bal & ((1ull << lane) - 1ull));
        int slot = cnt + rank;
        if (valid && slot < NS) sidx[wid * NS + slot] = n;
        cnt += __builtin_popcountll(bal);
    }
    int filled = cnt < NS ? cnt : NS;
    __syncthreads();   // sidx visible
    if (lane < NS) {
        int i = (lane < filled) ? sidx[wid * NS + lane] : (cnt > 0 ? first : 0);
        idx[(size_t)pid * NS + lane] = i;
        float dx = (xbs[i * 3 + 0] - px) * 20.0f;
        float dy = (xbs[i * 3 + 1] - py) * 20.0f;
        float dz = (xbs[i * 3 + 2] - pz) * 20.0f;
        float g0 = dx * r00 + dy * r10 + dz * r20;
        float g1 = dx * r01 + dy * r11 + dz * r21;
        float g2 = dx * r02 + dy * r12 + dz * r22;
        uint2 v;
        v.x = pk2bf(g0, g1);
        v.y = pk2bf(g2, 0.f);
        *(uint2*)(gxyz + ((size_t)pid * NS + lane) * 4) = v;
    }
}

// ---------------- fused GEMM1 (+optional norm1+GEMM2) over one 64-row m-tile ----------------
// GEMM1 BK=64: 4 feat phases + 1 xyz phase. Stride-64 LDS rows pre-swizzle the GLOBAL source slot
// (linear LDS dest) and MFMA reads XOR the same pattern: slot' = slot ^ (row&7).
// Column ownership: col = j*64 + wave*16 + tl (round-6-proven remap).
// FULL=0: stats1 partials (+y1 fragment spill when STORE=1, packed via HW cvt_pk).
// FULL=1: recompute GEMM1, norm1+relu -> LDS -> GEMM2 (fallback path, BK=32 GEMM2).
template <int FULL, int STORE>
__global__ __launch_bounds__(256) void fused_k(
    const u16* __restrict__ featT, const u16* __restrict__ gxyz, const int* __restrict__ idx,
    const u16* __restrict__ Wp1, const u16* __restrict__ Wp2, const float* __restrict__ ab1,
    float* __restrict__ psum, float* __restrict__ psq,
    float* __restrict__ ymax, float* __restrict__ ymin, uint2* __restrict__ y1f)
{
    __shared__ __attribute__((aligned(16))) u16 As[64 * 64];     //  8 KB
    __shared__ __attribute__((aligned(16))) u16 Bs[256 * 64];    // 32 KB
    __shared__ __attribute__((aligned(16))) u16 y1s[FULL ? 64 * 264 : 16];
    __shared__ int rowbase_s[64];

    const int tid = threadIdx.x;
    const int lane = tid & 63, wave = tid >> 6;
    const int quad = lane >> 4, tl = lane & 15;
    const int bx = blockIdx.x;
    const int m0 = bx * 64;

    if (tid < 64) {
        int m = m0 + tid;
        int gi = idx[m];
        int b = m >> 16;
        rowbase_s[tid] = (b * NPTS + gi) * CFEAT;
    }
    __syncthreads();

    // staging geometry: thread covers (row = tid>>3 [+32], dest slot = tid&7); source slot
    // pre-swizzled so LDS holds slot s at position s^(row&7).
    const int sr8 = tid >> 3;                 // 0..31
    const int koffA = (((tid & 7) ^ (sr8 & 7)) * 8);

    f32x4 acc[4][4];
    #pragma unroll
    for (int i = 0; i < 4; i++)
        #pragma unroll
        for (int j = 0; j < 4; j++) acc[i][j] = (f32x4){0.f, 0.f, 0.f, 0.f};

    // ---- GEMM1: 4 feat phases (BK=64) ----
    for (int t = 0; t < 4; t++) {
        const int k0 = t * 64;
        __syncthreads();
        gload16(featT + rowbase_s[sr8] + k0 + koffA, As + tid * 8);
        gload16(featT + rowbase_s[sr8 + 32] + k0 + koffA, As + 2048 + tid * 8);
        #pragma unroll
        for (int c = 0; c < 8; c++)
            gload16(Wp1 + (c * 32 + sr8) * 288 + k0 + koffA, Bs + c * 2048 + tid * 8);
        __syncthreads();   // vmcnt(0) drain: tiles landed
        #pragma unroll
        for (int kk = 0; kk < 2; kk++) {
            bf16x8 af[4], bv[4];
            #pragma unroll
            for (int i = 0; i < 4; i++)
                af[i] = *(const bf16x8*)(As + (i * 16 + tl) * 64 + (((kk * 4 + quad) ^ (tl & 7)) * 8));
            #pragma unroll
            for (int j = 0; j < 4; j++)
                bv[j] = *(const bf16x8*)(Bs + (j * 64 + wave * 16 + tl) * 64 + (((kk * 4 + quad) ^ (tl & 7)) * 8));
            #pragma unroll
            for (int i = 0; i < 4; i++)
                #pragma unroll
                for (int j = 0; j < 4; j++)
                    acc[i][j] = __builtin_amdgcn_mfma_f32_16x16x32_bf16(af[i], bv[j], acc[i][j], 0, 0, 0);
        }
    }
    // ---- xyz phase (K=32, register-staged with swizzled ds_write) ----
    {
        __syncthreads();
        const int srow = tid >> 2, sc16 = tid & 3;
        uint4 va = make_uint4(0, 0, 0, 0);
        if (sc16 == 0) {
            uint2 g2 = *(const uint2*)(gxyz + (size_t)(m0 + srow) * 4);
            va.x = g2.x; va.y = g2.y;
        }
        *(uint4*)(As + srow * 64 + ((sc16 ^ (srow & 7)) * 8)) = va;
        #pragma unroll
        for (int s = 0; s < 4; s++) {
            uint4 w = *(const uint4*)(Wp1 + tid * 288 + 256 + s * 8);
            *(uint4*)(Bs + tid * 64 + ((s ^ (tid & 7)) * 8)) = w;
        }
        __syncthreads();
        bf16x8 af[4], bv[4];
        #pragma unroll
        for (int i = 0; i < 4; i++)
            af[i] = *(const bf16x8*)(As + (i * 16 + tl) * 64 + ((quad ^ (tl & 7)) * 8));
        #pragma unroll
        for (int j = 0; j < 4; j++)
            bv[j] = *(const bf16x8*)(Bs + (j * 64 + wave * 16 + tl) * 64 + ((quad ^ (tl & 7)) * 8));
        #pragma unroll
        for (int i = 0; i < 4; i++)
            #pragma unroll
            for (int j = 0; j < 4; j++)
                acc[i][j] = __builtin_amdgcn_mfma_f32_16x16x32_bf16(af[i], bv[j], acc[i][j], 0, 0, 0);
    }

    if (!FULL) {
        #pragma unroll
        for (int j = 0; j < 4; j++) {
            float s = 0.f, q2 = 0.f;
            #pragma unroll
            for (int i = 0; i < 4; i++) {
                float v0 = acc[i][j][0], v1 = acc[i][j][1], v2 = acc[i][j][2], v3 = acc[i][j][3];
                if (STORE) {
                    u32 lo = pk2bf(v0, v1);      // HW RNE pack (1 instr per pair)
                    u32 hi = pk2bf(v2, v3);
                    y1f[((size_t)(bx * 4 + wave) * 16 + i * 4 + j) * 64 + lane] = make_uint2(lo, hi);
                    // stats on the rounded values for self-consistency with pass 2
                    v0 = bf2f((u16)(lo & 0xffff)); v1 = bf2f((u16)(lo >> 16));
                    v2 = bf2f((u16)(hi & 0xffff)); v3 = bf2f((u16)(hi >> 16));
                }
                s += v0 + v1 + v2 + v3;
                q2 += v0 * v0 + v1 * v1 + v2 * v2 + v3 * v3;
            }
            s += __shfl_xor(s, 16); s += __shfl_xor(s, 32);
            q2 += __shfl_xor(q2, 16); q2 += __shfl_xor(q2, 32);
            if (quad == 0) {
                int col = j * 64 + wave * 16 + tl;
                psum[(size_t)bx * 256 + col] = s;
                psq[(size_t)bx * 256 + col] = q2;
            }
        }
        return;
    }

    // ---- norm1 + relu -> y1s (bf16), remapped cols ----
    #pragma unroll
    for (int j = 0; j < 4; j++) {
        int col = j * 64 + wave * 16 + tl;
        float a = ab1[col], bb = ab1[256 + col];
        #pragma unroll
        for (int i = 0; i < 4; i++)
            #pragma unroll
            for (int r = 0; r < 4; r++) {
                float v = fmaxf(fmaf(acc[i][j][r], a, bb), 0.f);
                y1s[(i * 16 + quad * 4 + r) * 264 + col] = f2bf(v);
            }
    }

    // ---- GEMM2 (BK=32; uses first 16KB of Bs with stride-32 mapping) ----
    const int srow = tid >> 2, sc16 = tid & 3;
    f32x4 acc2[4][4];
    #pragma unroll
    for (int i = 0; i < 4; i++)
        #pragma unroll
        for (int j = 0; j < 4; j++) acc2[i][j] = (f32x4){0.f, 0.f, 0.f, 0.f};
    for (int ks = 0; ks < 8; ks++) {
        const int k0 = ks * 32;
        __syncthreads();
        #pragma unroll
        for (int q = 0; q < 4; q++)
            gload16(Wp2 + (srow + q * 64) * 256 + k0 + sc16 * 8, Bs + q * 2048 + tid * 8);
        __syncthreads();
        bf16x8 af[4], bv[4];
        #pragma unroll
        for (int i = 0; i < 4; i++) af[i] = *(const bf16x8*)(y1s + (i * 16 + tl) * 264 + k0 + quad * 8);
        #pragma unroll
        for (int j = 0; j < 4; j++) bv[j] = *(const bf16x8*)(Bs + (j * 64 + wave * 16 + tl) * 32 + quad * 8);
        #pragma unroll
        for (int i = 0; i < 4; i++)
            #pragma unroll
            for (int j = 0; j < 4; j++)
                acc2[i][j] = __builtin_amdgcn_mfma_f32_16x16x32_bf16(af[i], bv[j], acc2[i][j], 0, 0, 0);
    }

    // ---- epilogue2 ----
    #pragma unroll
    for (int j = 0; j < 4; j++) {
        int col = j * 64 + wave * 16 + tl;
        float s = 0.f, q2 = 0.f;
        float mx0 = -3.0e38f, mn0 = 3.0e38f, mx1 = -3.0e38f, mn1 = 3.0e38f;
        #pragma unroll
        for (int i = 0; i < 4; i++)
            #pragma unroll
            for (int r = 0; r < 4; r++) {
                float v = acc2[i][j][r];
                s += v; q2 += v * v;
                if (i < 2) { mx0 = fmaxf(mx0, v); mn0 = fminf(mn0, v); }
                else       { mx1 = fmaxf(mx1, v); mn1 = fminf(mn1, v); }
            }
        s += __shfl_xor(s, 16); s += __shfl_xor(s, 32);
        q2 += __shfl_xor(q2, 16); q2 += __shfl_xor(q2, 32);
        mx0 = fmaxf(mx0, __shfl_xor(mx0, 16)); mx0 = fmaxf(mx0, __shfl_xor(mx0, 32));
        mn0 = fminf(mn0, __shfl_xor(mn0, 16)); mn0 = fminf(mn0, __shfl_xor(mn0, 32));
        mx1 = fmaxf(mx1, __shfl_xor(mx1, 16)); mx1 = fmaxf(mx1, __shfl_xor(mx1, 32));
        mn1 = fminf(mn1, __shfl_xor(mn1, 16)); mn1 = fminf(mn1, __shfl_xor(mn1, 32));
        if (quad == 0) {
            psum[(size_t)bx * 256 + col] = s;
            psq[(size_t)bx * 256 + col] = q2;
            size_t p0 = (size_t)(bx * 2) * 256 + col;
            size_t p1 = (size_t)(bx * 2 + 1) * 256 + col;
            ymax[p0] = mx0; ymin[p0] = mn0;
            ymax[p1] = mx1; ymin[p1] = mn1;
        }
    }
}

// ---------------- pass 2 (big-ws path): reload y1 frags, norm+relu -> K-halved LDS -> BK=64 GEMM2 ----
// y1s = 64x136 half-buffer; Bs = 256x64 source-slot-swizzled; deposits use HW cvt_pk (1 op/value).
__global__ __launch_bounds__(256) void fused2_k(
    const uint2* __restrict__ y1f, const u16* __restrict__ Wp2, const float* __restrict__ ab1,
    float* __restrict__ psum, float* __restrict__ psq,
    float* __restrict__ ymax, float* __restrict__ ymin)
{
    __shared__ __attribute__((aligned(16))) u16 Bs[256 * 64];    // 32 KB
    __shared__ __attribute__((aligned(16))) u16 y1s[64 * 136];   // 17 KB (half of y1)
    const int tid = threadIdx.x;
    const int lane = tid & 63, wave = tid >> 6;
    const int quad = lane >> 4, tl = lane & 15;
    const int bx = blockIdx.x;
    const int sr8 = tid >> 3;
    const int koffB = (((tid & 7) ^ (sr8 & 7)) * 8);

    // reload pass-1 fragments once (coalesced), keep normalized values in registers
    float yv[4][4][4];   // [j][i][r]
    #pragma unroll
    for (int j = 0; j < 4; j++) {
        int col = j * 64 + wave * 16 + tl;
        float a = ab1[col], bb = ab1[256 + col];
        #pragma unroll
        for (int i = 0; i < 4; i++) {
            uint2 v = y1f[((size_t)(bx * 4 + wave) * 16 + i * 4 + j) * 64 + lane];
            yv[j][i][0] = fmaxf(fmaf(bf2f((u16)(v.x & 0xffff)), a, bb), 0.f);
            yv[j][i][1] = fmaxf(fmaf(bf2f((u16)(v.x >> 16)), a, bb), 0.f);
            yv[j][i][2] = fmaxf(fmaf(bf2f((u16)(v.y & 0xffff)), a, bb), 0.f);
            yv[j][i][3] = fmaxf(fmaf(bf2f((u16)(v.y >> 16)), a, bb), 0.f);
        }
    }
    // deposit K-half 0 (channels 0..127 = j=0,1 of every wave), HW cvt
    #pragma unroll
    for (int j = 0; j < 2; j++) {
        int col = j * 64 + wave * 16 + tl;
        #pragma unroll
        for (int i = 0; i < 4; i++)
            #pragma unroll
            for (int r = 0; r < 4; r++)
                y1s[(i * 16 + quad * 4 + r) * 136 + col] = (u16)pk2bf(yv[j][i][r], 0.f);
    }

    f32x4 acc2[4][4];
    #pragma unroll
    for (int i = 0; i < 4; i++)
        #pragma unroll
        for (int j = 0; j < 4; j++) acc2[i][j] = (f32x4){0.f, 0.f, 0.f, 0.f};

    for (int t = 0; t < 4; t++) {
        const int k0 = t * 64;
        __syncthreads();   // prev phase's reads done (first iter: y1s half-0 writes visible soon)
        if (t == 2) {      // phase-1 reads of half-0 complete -> deposit half-1 (channels 128..255)
            #pragma unroll
            for (int j = 2; j < 4; j++) {
                int lc = (j - 2) * 64 + wave * 16 + tl;
                #pragma unroll
                for (int i = 0; i < 4; i++)
                    #pragma unroll
                    for (int r = 0; r < 4; r++)
                        y1s[(i * 16 + quad * 4 + r) * 136 + lc] = (u16)pk2bf(yv[j][i][r], 0.f);
            }
        }
        #pragma unroll
        for (int c = 0; c < 8; c++)
            gload16(Wp2 + (c * 32 + sr8) * 256 + k0 + koffB, Bs + c * 2048 + tid * 8);
        __syncthreads();   // drains gload16 (vmcnt) + ds_writes (lgkm)
        const int klb = (t & 1) * 64;    // k-base within the half-buffer
        #pragma unroll
        for (int kk = 0; kk < 2; kk++) {
            bf16x8 af[4], bv[4];
            #pragma unroll
            for (int i = 0; i < 4; i++)
                af[i] = *(const bf16x8*)(y1s + (i * 16 + tl) * 136 + klb + kk * 32 + quad * 8);
            #pragma unroll
            for (int j = 0; j < 4; j++)
                bv[j] = *(const bf16x8*)(Bs + (j * 64 + wave * 16 + tl) * 64 + (((kk * 4 + quad) ^ (tl & 7)) * 8));
            #pragma unroll
            for (int i = 0; i < 4; i++)
                #pragma unroll
                for (int j = 0; j < 4; j++)
                    acc2[i][j] = __builtin_amdgcn_mfma_f32_16x16x32_bf16(af[i], bv[j], acc2[i][j], 0, 0, 0);
        }
    }

    #pragma unroll
    for (int j = 0; j < 4; j++) {
        int col = j * 64 + wave * 16 + tl;
        float s = 0.f, q2 = 0.f;
        float mx0 = -3.0e38f, mn0 = 3.0e38f, mx1 = -3.0e38f, mn1 = 3.0e38f;
        #pragma unroll
        for (int i = 0; i < 4; i++)
            #pragma unroll
            for (int r = 0; r < 4; r++) {
                float v = acc2[i][j][r];
                s += v; q2 += v * v;
                if (i < 2) { mx0 = fmaxf(mx0, v); mn0 = fminf(mn0, v); }
                else       { mx1 = fmaxf(mx1, v); mn1 = fminf(mn1, v); }
            }
        s += __shfl_xor(s, 16); s += __shfl_xor(s, 32);
        q2 += __shfl_xor(q2, 16); q2 += __shfl_xor(q2, 32);
        mx0 = fmaxf(mx0, __shfl_xor(mx0, 16)); mx0 = fmaxf(mx0, __shfl_xor(mx0, 32));
        mn0 = fminf(mn0, __shfl_xor(mn0, 16)); mn0 = fminf(mn0, __shfl_xor(mn0, 32));
        mx1 = fmaxf(mx1, __shfl_xor(mx1, 16)); mx1 = fmaxf(mx1, __shfl_xor(mx1, 32));
        mn1 = fminf(mn1, __shfl_xor(mn1, 16)); mn1 = fminf(mn1, __shfl_xor(mn1, 32));
        if (quad == 0) {
            psum[(size_t)bx * 256 + col] = s;
            psq[(size_t)bx * 256 + col] = q2;
            size_t p0 = (size_t)(bx * 2) * 256 + col;
            size_t p1 = (size_t)(bx * 2 + 1) * 256 + col;
            ymax[p0] = mx0; ymin[p0] = mn0;
            ymax[p1] = mx1; ymin[p1] = mn1;
        }
    }
}

// ---------------- stats reduction: 64 blocks x 64 rows (coalesced), then 1-block 64-iter finish ------
__global__ __launch_bounds__(256) void reduce1_k(const float* __restrict__ psum, const float* __restrict__ psq,
                                                 float* __restrict__ ps2, float* __restrict__ pq2) {
    int j = blockIdx.x, t = threadIdx.x;
    float s = 0.f, q = 0.f;
    #pragma unroll 4
    for (int kk = 0; kk < 64; kk++) {
        size_t r = (size_t)(j * 64 + kk) * 256 + t;
        s += psum[r]; q += psq[r];
    }
    ps2[j * 256 + t] = s;
    pq2[j * 256 + t] = q;
}

__global__ __launch_bounds__(256) void reduce2_k(const float* __restrict__ ps2, const float* __restrict__ pq2,
                                                 const float* __restrict__ gamma, const float* __restrict__ beta,
                                                 float* __restrict__ ab) {
    int c = threadIdx.x;
    float S = 0.f, Q = 0.f;
    for (int j = 0; j < 64; j++) {
        S += ps2[j * 256 + c];
        Q += pq2[j * 256 + c];
    }
    float mu = S * INV_N;
    float var = Q * INV_N - mu * mu;
    float a = gamma[c] * rsqrtf(var + 1e-5f);
    ab[c] = a;
    ab[256 + c] = beta[c] - mu * a;
}

// ---------------- final: relu(a*(a>=0?max:min)+b), transpose -> (B,O,N) ----------------
__global__ __launch_bounds__(256) void final_k(const float* __restrict__ ymax, const float* __restrict__ ymin,
                                               const float* __restrict__ ab, float* __restrict__ out) {
    __shared__ float sm[32 * 33];
    int b = blockIdx.z;
    int n0 = blockIdx.x * 32, o0 = blockIdx.y * 32;
    int t = threadIdx.x, x = t & 31, y = t >> 5;
    #pragma unroll
    for (int rr = 0; rr < 4; rr++) {
        int n = n0 + y + rr * 8;
        int o = o0 + x;
        float a = ab[o], bb = ab[256 + o];
        size_t p = (size_t)(b * NPTS + n) * 256 + o;
        float v = (a >= 0.f) ? ymax[p] : ymin[p];
        sm[(y + rr * 8) * 33 + x] = fmaxf(fmaf(v, a, bb), 0.f);
    }
    __syncthreads();
    #pragma unroll
    for (int rr = 0; rr < 4; rr++)
        out[((size_t)(b * 256 + o0 + y + rr * 8)) * NPTS + n0 + x] = sm[x * 33 + (y + rr * 8)];
}

extern "C" void kernel_launch(void* const* d_in, const int* in_sizes, int n_in,
                              void* d_out, int out_size, void* d_ws, size_t ws_size,
                              hipStream_t stream) {
    const float* xyz    = (const float*)d_in[0];
    const float* feat   = (const float*)d_in[1];
    const float* rot    = (const float*)d_in[2];
    const float* W1     = (const float*)d_in[3];
    const float* gamma1 = (const float*)d_in[4];
    const float* beta1  = (const float*)d_in[5];
    const float* W2     = (const float*)d_in[6];
    const float* gamma2 = (const float*)d_in[7];
    const float* beta2  = (const float*)d_in[8];
    float* out = (float*)d_out;

    char* ws = (char*)d_ws;
    u16*   featT = (u16*)(ws + 0);           //  4,194,304
    int*   idxp  = (int*)(ws + 4194304);     //  1,048,576
    u16*   gxyz  = (u16*)(ws + 5242880);     //  2,097,152
    u16*   Wp1   = (u16*)(ws + 7340032);     //    147,456
    u16*   Wp2   = (u16*)(ws + 7487488);     //    131,072
    float* ab1   = (float*)(ws + 7618560);   //      2,048
    float* ab2   = (float*)(ws + 7620608);   //      2,048
    float* psum  = (float*)(ws + 7622656);   //  4,194,304
    float* psq   = (float*)(ws + 11816960);  //  4,194,304
    float* ymax  = (float*)(ws + 16011264);  //  8,388,608
    float* ymin  = (float*)(ws + 24399872);  //  8,388,608
    uint2* y1f   = (uint2*)(ws + 32788480);  // 134,217,728 (big path only)
    const size_t BIG_NEED = 32788480ull + 134217728ull;   // 167,006,208

    // stage-2 reduction scratch (64x256 f32 each), borrowed dead regions:
    //  - stats1 reduce runs before pass 2 writes ymin -> borrow ymin region
    //  - stats2 reduce runs after gxyz last use -> borrow gxyz region
    float* r1s = (float*)(ws + 24399872);
    float* r1q = r1s + 16384;
    float* r2s = (float*)(ws + 5242880);
    float* r2q = r2s + 16384;

    query_k<<<2048, 256, 0, stream>>>(xyz, rot, feat, idxp, gxyz, featT, W1, W2, Wp1, Wp2);

    if (ws_size >= BIG_NEED) {
        // pass 1: GEMM1 (BK=64 swizzled phases) + fragment-layout y1 spill + stats1
        fused_k<0, 1><<<NBLK, 256, 0, stream>>>(featT, gxyz, idxp, Wp1, Wp2, ab1, psum, psq, ymax, ymin, y1f);
        reduce1_k<<<64, 256, 0, stream>>>(psum, psq, r1s, r1q);
        reduce2_k<<<1, 256, 0, stream>>>(r1s, r1q, gamma1, beta1, ab1);
        // pass 2: reload y1 frags -> norm/relu -> BK=64 GEMM2 (K-halved y1s) + stats2 + max/min
        fused2_k<<<NBLK, 256, 0, stream>>>(y1f, Wp2, ab1, psum, psq, ymax, ymin);
        reduce1_k<<<64, 256, 0, stream>>>(psum, psq, r2s, r2q);
        reduce2_k<<<1, 256, 0, stream>>>(r2s, r2q, gamma2, beta2, ab2);
    } else {
        // fallback: recompute GEMM1 in pass 2 (proven path)
        fused_k<0, 0><<<NBLK, 256, 0, stream>>>(featT, gxyz, idxp, Wp1, Wp2, ab1, psum, psq, ymax, ymin, nullptr);
        reduce1_k<<<64, 256, 0, stream>>>(psum, psq, r1s, r1q);
        reduce2_k<<<1, 256, 0, stream>>>(r1s, r1q, gamma1, beta1, ab1);
        fused_k<1, 0><<<NBLK, 256, 0, stream>>>(featT, gxyz, idxp, Wp1, Wp2, ab1, psum, psq, ymax, ymin, nullptr);
        reduce1_k<<<64, 256, 0, stream>>>(psum, psq, r2s, r2q);
        reduce2_k<<<1, 256, 0, stream>>>(r2s, r2q, gamma2, beta2, ab2);
    }
    final_k<<<dim3(64, 8, 4), 256, 0, stream>>>(ymax, ymin, ab2, out);
}